// Round 15
// baseline (433.471 us; speedup 1.0000x reference)
//
#include <hip/hip_runtime.h>
#include <hip/hip_bf16.h>

typedef unsigned short u16;
typedef unsigned int u32;
typedef __attribute__((ext_vector_type(8))) short short8;   // 8 bf16 = 4 VGPR
typedef __attribute__((ext_vector_type(4))) float f32x4;

#define WAITV(N) asm volatile("s_waitcnt vmcnt(" #N ")" ::: "memory")

__device__ __forceinline__ float sigmoidf_(float x) { return 1.0f / (1.0f + expf(-x)); }
// fast gates: v_exp_f32 + v_rcp_f32 (~1 ulp each)
__device__ __forceinline__ float fsig(float x) {
    return __builtin_amdgcn_rcpf(1.0f + __expf(-x));
}
__device__ __forceinline__ float ftanh(float x) {
    x = fminf(fmaxf(x, -15.0f), 15.0f);
    float t = __expf(2.0f * x);
    return (t - 1.0f) * __builtin_amdgcn_rcpf(t + 1.0f);
}

__device__ __forceinline__ float bf2f(u16 u) {
    union { u32 i; float f; } v; v.i = ((u32)u) << 16; return v.f;
}
__device__ __forceinline__ u16 f2bf(float f) {
    union { float f; u32 i; } v; v.f = f;
    u32 lsb = (v.i >> 16) & 1u;
    v.i += 0x7fffu + lsb;            // RNE
    return (u16)(v.i >> 16);
}

// async 16B global->LDS (hardware DMA; LDS dest = wave base + lane*16, global src per-lane)
__device__ __forceinline__ void gload16(const u16* g, u16* l) {
    __builtin_amdgcn_global_load_lds(
        (const __attribute__((address_space(1))) u32*)g,
        (__attribute__((address_space(3))) u32*)l, 16, 0, 0);
}

// ---------------- merged prep: all weight conversions + one-hot + leaf table ----------------
__global__ __launch_bounds__(256) void prep(
    const float* __restrict__ ewh, const float* __restrict__ dwh,
    const float* __restrict__ dwi, const float* __restrict__ ewi,
    const float* __restrict__ h2o_w, const int* __restrict__ symbols,
    const float* __restrict__ ebi, const float* __restrict__ ebh,
    u16* __restrict__ ewh_b, u16* __restrict__ dwh_b, u16* __restrict__ dwi_b,
    u16* __restrict__ ewi_b, u16* __restrict__ wo_b, u16* __restrict__ oneh,
    u16* __restrict__ ltab)
{
    int idx = blockIdx.x * 256 + threadIdx.x;
    if (idx < 1572864) { ewh_b[idx] = f2bf(ewh[idx]); return; }
    idx -= 1572864;
    if (idx < 1572864) { dwh_b[idx] = f2bf(dwh[idx]); return; }
    idx -= 1572864;
    if (idx < 98304) { dwi_b[idx] = f2bf(dwi[idx]); return; }
    idx -= 98304;
    if (idx < 49152) { ewi_b[idx] = f2bf(ewi[idx]); return; }
    idx -= 49152;
    if (idx < 16384) { wo_b[idx] = f2bf(h2o_w[idx]); return; }
    idx -= 16384;
    if (idx < 1040384) {
        int col = idx & 31, row = idx >> 5;
        oneh[idx] = (col == symbols[row]) ? (u16)0x3F80 : (u16)0;
        return;
    }
    idx -= 1040384;
    if (idx < 16384) {
        int c = idx & 511, sym = idx >> 9;
        float r = sigmoidf_(ewi[c * 32 + sym]          + ebi[c]        + ebh[c]);
        float z = sigmoidf_(ewi[(512 + c) * 32 + sym]  + ebi[512 + c]  + ebh[512 + c]);
        float n = tanhf(    ewi[(1024 + c) * 32 + sym] + ebi[1024 + c] + r * ebh[1024 + c]);
        ltab[idx] = f2bf((1.0f - z) * n);
    }
}

// ---------------- Encoder: 2-buffer counted-vmcnt MFMA GEMM + GRU ----------------
// SWAPPED operands: D[row=c][col=m]; lane holds 4 consecutive c (reg) for one m (lane&15).
// Step: barrier -> issue(t+1) -> vmcnt(L) -> compute(t).  LDS 40KB(RF4) -> 4 blocks/CU.
template<int RF, bool LEAF>
__global__ __launch_bounds__(256, 4) void enc_tile(
    const u16* __restrict__ A, const u16* __restrict__ W,
    const u16* __restrict__ oneh, const u16* __restrict__ Wi,
    const u16* __restrict__ tab, const int* __restrict__ symbols,
    const float* __restrict__ ebi, const float* __restrict__ ebh,
    u16* __restrict__ hout, int dlog, int node_base)
{
    constexpr int BM = RF * 32;
    constexpr int NCA = BM / 64;
    constexpr int NS = 32;                  // K stages (1024/32)
    __shared__ alignas(16) u16 Als[2][BM * 32];
    __shared__ alignas(16) u16 Bls[2][192 * 32];
    const int tid  = threadIdx.x;
    const int lane = tid & 63;
    const int wid  = tid >> 6;
    const int wr = wid >> 1, wc = wid & 1;
    const int lr = lane & 15, lk = lane >> 4;
    const int m0 = blockIdx.x * BM;
    const int c0 = blockIdx.y * 64;
    const int mask = (1 << dlog) - 1;

    size_t a_goff[NCA]; int a_loff[NCA];
    int symL[NCA], symR[NCA];
#pragma unroll
    for (int j = 0; j < NCA; ++j) {
        int a = wid * NCA + j;
        int r_ = a * 16 + (lane >> 2);
        int kps = (lane & 3) ^ ((r_ >> 1) & 3);
        a_loff[j] = a * 512 + lane * 8;
        if constexpr (LEAF) {
            int rg = m0 + r_;
            int b_ = rg >> dlog, jj = rg & mask;
            int cbase = b_ * 127 + 2 * (node_base + jj) + 1;
            symL[j] = symbols[cbase];
            symR[j] = symbols[cbase + 1];
            a_goff[j] = kps * 8;
        } else {
            a_goff[j] = (size_t)(m0 + r_) * 1024 + kps * 8;
            symL[j] = symR[j] = 0;
        }
    }
    size_t b_goff[3]; int b_loff[3];
#pragma unroll
    for (int j = 0; j < 3; ++j) {
        int b = wid * 3 + j;
        int rr = b * 16 + (lane >> 2);
        int kps = (lane & 3) ^ ((rr >> 1) & 3);
        int grow = (rr >> 6) * 512 + c0 + (rr & 63);
        b_goff[j] = (size_t)grow * 1024 + kps * 8;
        b_loff[j] = b * 512 + lane * 8;
    }
    int a_roff[RF];
#pragma unroll
    for (int i = 0; i < RF; ++i) {
        int row = wr * (RF * 16) + i * 16 + lr;
        a_roff[i] = row * 32 + (lk ^ ((row >> 1) & 3)) * 8;
    }
    int b_roff[3][2];
#pragma unroll
    for (int s = 0; s < 3; ++s)
#pragma unroll
        for (int cf = 0; cf < 2; ++cf) {
            int row = s * 64 + wc * 32 + cf * 16 + lr;
            b_roff[s][cf] = row * 32 + (lk ^ ((row >> 1) & 3)) * 8;
        }

    f32x4 acc[4][2][RF];
#pragma unroll
    for (int s = 0; s < 4; ++s)
#pragma unroll
        for (int cf = 0; cf < 2; ++cf)
#pragma unroll
            for (int i = 0; i < RF; ++i) acc[s][cf][i] = (f32x4){0.f, 0.f, 0.f, 0.f};

    auto issue = [&](int stg) {
        const int buf = stg & 1;
        const int nk = stg * 32;
#pragma unroll
        for (int j = 0; j < NCA; ++j) {
            if constexpr (LEAF) {
                const u16* src = (nk < 512)
                    ? tab + (size_t)symL[j] * 512 + nk + a_goff[j]
                    : tab + (size_t)symR[j] * 512 + (nk - 512) + a_goff[j];
                gload16(src, &Als[buf][a_loff[j]]);
            } else {
                gload16(A + a_goff[j] + nk, &Als[buf][a_loff[j]]);
            }
        }
#pragma unroll
        for (int j = 0; j < 3; ++j) gload16(W + b_goff[j] + nk, &Bls[buf][b_loff[j]]);
    };
    auto compute = [&](int buf) {
        short8 a[RF];
#pragma unroll
        for (int i = 0; i < RF; ++i)
            a[i] = *reinterpret_cast<const short8*>(&Als[buf][a_roff[i]]);
#pragma unroll
        for (int s = 0; s < 3; ++s)
#pragma unroll
            for (int cf = 0; cf < 2; ++cf) {
                short8 b = *reinterpret_cast<const short8*>(&Bls[buf][b_roff[s][cf]]);
#pragma unroll
                for (int i = 0; i < RF; ++i)   // SWAPPED: weights first
                    acc[s][cf][i] = __builtin_amdgcn_mfma_f32_16x16x32_bf16(b, a[i], acc[s][cf][i], 0, 0, 0);
            }
    };

    issue(0);
    for (int t = 0; t < NS; ++t) {
        __builtin_amdgcn_s_barrier();       // all waves done with compute(t-1): buf (t+1)&1 free
        if (t + 1 < NS) issue(t + 1);
        if constexpr (RF == 4) WAITV(5); else WAITV(4);   // stage t landed; t+1 in flight
        compute(t & 1);
    }

    // ---- rank-32 one-hot gi contribution (swapped): slot map 0->0, 1->1, 2->3 ----
    {
        short8 oh[RF];
#pragma unroll
        for (int i = 0; i < RF; ++i) {
            int m = m0 + wr * (RF * 16) + i * 16 + lr;
            int b_ = m >> dlog, j_ = m & mask;
            oh[i] = *reinterpret_cast<const short8*>(
                oneh + (size_t)(b_ * 127 + node_base + j_) * 32 + lk * 8);
        }
#pragma unroll
        for (int s = 0; s < 3; ++s) {
            const int d = (s == 2) ? 3 : s;
#pragma unroll
            for (int cf = 0; cf < 2; ++cf) {
                short8 wb = *reinterpret_cast<const short8*>(
                    Wi + (size_t)(s * 512 + c0 + wc * 32 + cf * 16 + lr) * 32 + lk * 8);
#pragma unroll
                for (int i = 0; i < RF; ++i)
                    acc[d][cf][i] = __builtin_amdgcn_mfma_f32_16x16x32_bf16(wb, oh[i], acc[d][cf][i], 0, 0, 0);
            }
        }
    }

    // ---- epilogue: lane owns 4 consecutive c (reg r) for one m = base + lr ----
    float4 ebr4[2], ebz4[2], ebin4[2], ebhn4[2];
    int cb[2];
#pragma unroll
    for (int cf = 0; cf < 2; ++cf) {
        cb[cf] = c0 + wc * 32 + cf * 16 + lk * 4;
        float4 bi0 = *reinterpret_cast<const float4*>(ebi + cb[cf]);
        float4 bh0 = *reinterpret_cast<const float4*>(ebh + cb[cf]);
        float4 bi1 = *reinterpret_cast<const float4*>(ebi + 512 + cb[cf]);
        float4 bh1 = *reinterpret_cast<const float4*>(ebh + 512 + cb[cf]);
        ebr4[cf] = make_float4(bi0.x + bh0.x, bi0.y + bh0.y, bi0.z + bh0.z, bi0.w + bh0.w);
        ebz4[cf] = make_float4(bi1.x + bh1.x, bi1.y + bh1.y, bi1.z + bh1.z, bi1.w + bh1.w);
        ebin4[cf] = *reinterpret_cast<const float4*>(ebi + 1024 + cb[cf]);
        ebhn4[cf] = *reinterpret_cast<const float4*>(ebh + 1024 + cb[cf]);
    }
#pragma unroll
    for (int i = 0; i < RF; ++i) {
        int m = m0 + wr * (RF * 16) + i * 16 + lr;
        int symLm = 0, symRm = 0;
        if constexpr (LEAF) {
            int b_ = m >> dlog, jj = m & mask;
            int cbase_ = b_ * 127 + 2 * (node_base + jj) + 1;
            symLm = symbols[cbase_];
            symRm = symbols[cbase_ + 1];
        }
#pragma unroll
        for (int cf = 0; cf < 2; ++cf) {
            ushort4 hl4, hr4;
            if constexpr (LEAF) {
                hl4 = *reinterpret_cast<const ushort4*>(tab + (size_t)symLm * 512 + cb[cf]);
                hr4 = *reinterpret_cast<const ushort4*>(tab + (size_t)symRm * 512 + cb[cf]);
            } else {
                hl4 = *reinterpret_cast<const ushort4*>(A + (size_t)m * 1024 + cb[cf]);
                hr4 = *reinterpret_cast<const ushort4*>(A + (size_t)m * 1024 + 512 + cb[cf]);
            }
            const float eb_r[4] = {ebr4[cf].x, ebr4[cf].y, ebr4[cf].z, ebr4[cf].w};
            const float eb_z[4] = {ebz4[cf].x, ebz4[cf].y, ebz4[cf].z, ebz4[cf].w};
            const float eb_in[4] = {ebin4[cf].x, ebin4[cf].y, ebin4[cf].z, ebin4[cf].w};
            const float eb_hn[4] = {ebhn4[cf].x, ebhn4[cf].y, ebhn4[cf].z, ebhn4[cf].w};
            const u16 hlv[4] = {hl4.x, hl4.y, hl4.z, hl4.w};
            const u16 hrv[4] = {hr4.x, hr4.y, hr4.z, hr4.w};
            ushort4 outv;
            u16* ov = reinterpret_cast<u16*>(&outv);
#pragma unroll
            for (int r = 0; r < 4; ++r) {
                float rr_ = fsig(acc[0][cf][i][r] + eb_r[r]);
                float zz  = fsig(acc[1][cf][i][r] + eb_z[r]);
                float nn  = ftanh(acc[3][cf][i][r] + eb_in[r] + rr_ * (acc[2][cf][i][r] + eb_hn[r]));
                float hm = (bf2f(hlv[r]) + bf2f(hrv[r])) * 0.5f;
                ov[r] = f2bf((1.0f - zz) * nn + zz * hm);
            }
            *reinterpret_cast<ushort4*>(hout + (size_t)m * 512 + cb[cf]) = outv;
        }
    }
}

// ---------------- mid: mu/logvar/zlat ----------------
__global__ __launch_bounds__(256) void mid1(
    const u16* __restrict__ root, const float* __restrict__ h2mu_w,
    const float* __restrict__ h2mu_b, const float* __restrict__ h2lv_w,
    const float* __restrict__ h2lv_b, const float* __restrict__ eps,
    float* __restrict__ zlat, float* __restrict__ out_mu,
    float* __restrict__ out_lv)
{
    int b = blockIdx.x, t = threadIdx.x;
    __shared__ float rs[512];
    rs[t]       = bf2f(root[(size_t)b * 512 + t]);
    rs[t + 256] = bf2f(root[(size_t)b * 512 + t + 256]);
    __syncthreads();
    const float* w = (t < 128) ? (h2mu_w + (size_t)t * 512) : (h2lv_w + (size_t)(t - 128) * 512);
    float acc = 0.0f;
    for (int k = 0; k < 512; ++k) acc += rs[k] * w[k];
    acc += (t < 128) ? h2mu_b[t] : h2lv_b[t - 128];
    __shared__ float vals[256];
    vals[t] = acc;
    __syncthreads();
    if (t < 128) {
        float mu = vals[t], lv = vals[t + 128];
        float zl = mu + eps[b * 128 + t] * expf(0.5f * lv);
        zlat[b * 128 + t] = zl;
        out_mu[b * 128 + t] = mu;
        out_lv[b * 128 + t] = lv;
    }
}

__global__ __launch_bounds__(512) void mid2(
    const float* __restrict__ zlat, const float* __restrict__ z2h_w,
    const float* __restrict__ z2h_b, u16* __restrict__ hidden)
{
    int b = blockIdx.x, t = threadIdx.x;
    __shared__ float zs[128];
    if (t < 128) zs[t] = zlat[b * 128 + t];
    __syncthreads();
    float acc = z2h_b[t];
    for (int k = 0; k < 128; ++k) acc += zs[k] * z2h_w[(size_t)t * 128 + k];
    hidden[(size_t)b * 512 + t] = f2bf(acc);
}

// ---------------- decoder pred via swapped MFMA + softmax over lk-groups ----------------
__global__ __launch_bounds__(256) void pred_mfma(
    const u16* __restrict__ hidden, const u16* __restrict__ Wo,
    const float* __restrict__ h2o_b, u16* __restrict__ aout,
    float* __restrict__ preds_out, int dlog, int node_base, int write_a)
{
    const int lane = threadIdx.x & 63;
    const int wid  = threadIdx.x >> 6;
    const int lr = lane & 15, lk = lane >> 4;
    const int m0 = blockIdx.x * 64 + wid * 16;

    f32x4 acc0 = (f32x4){0.f, 0.f, 0.f, 0.f};
    f32x4 acc1 = (f32x4){0.f, 0.f, 0.f, 0.f};
    const u16* Arow = hidden + (size_t)(m0 + lr) * 512 + lk * 8;
    const u16* B0 = Wo + (size_t)lr * 512 + lk * 8;
    const u16* B1 = Wo + (size_t)(16 + lr) * 512 + lk * 8;
#pragma unroll
    for (int k0 = 0; k0 < 512; k0 += 32) {
        short8 a  = *reinterpret_cast<const short8*>(Arow + k0);
        short8 b0 = *reinterpret_cast<const short8*>(B0 + k0);
        short8 b1 = *reinterpret_cast<const short8*>(B1 + k0);
        acc0 = __builtin_amdgcn_mfma_f32_16x16x32_bf16(b0, a, acc0, 0, 0, 0);
        acc1 = __builtin_amdgcn_mfma_f32_16x16x32_bf16(b1, a, acc1, 0, 0, 0);
    }
    float4 bb0 = *reinterpret_cast<const float4*>(h2o_b + lk * 4);
    float4 bb1 = *reinterpret_cast<const float4*>(h2o_b + 16 + lk * 4);
    float p0[4], p1[4];
    p0[0] = acc0[0] + bb0.x; p0[1] = acc0[1] + bb0.y; p0[2] = acc0[2] + bb0.z; p0[3] = acc0[3] + bb0.w;
    p1[0] = acc1[0] + bb1.x; p1[1] = acc1[1] + bb1.y; p1[2] = acc1[2] + bb1.z; p1[3] = acc1[3] + bb1.w;
    float mx = fmaxf(fmaxf(fmaxf(p0[0], p0[1]), fmaxf(p0[2], p0[3])),
                     fmaxf(fmaxf(p1[0], p1[1]), fmaxf(p1[2], p1[3])));
    mx = fmaxf(mx, __shfl_xor(mx, 16));
    mx = fmaxf(mx, __shfl_xor(mx, 32));
    float e0[4], e1[4], s = 0.0f;
#pragma unroll
    for (int r = 0; r < 4; ++r) { e0[r] = __expf(p0[r] - mx); e1[r] = __expf(p1[r] - mx); s += e0[r] + e1[r]; }
    s += __shfl_xor(s, 16);
    s += __shfl_xor(s, 32);

    int m = m0 + lr;
    int b_ = m >> dlog, j_ = m & ((1 << dlog) - 1);
    size_t o = (size_t)(b_ * 127 + node_base + j_) * 32;
    *reinterpret_cast<float4*>(preds_out + o + lk * 4)      = make_float4(p0[0], p0[1], p0[2], p0[3]);
    *reinterpret_cast<float4*>(preds_out + o + 16 + lk * 4) = make_float4(p1[0], p1[1], p1[2], p1[3]);
    if (write_a) {
        float inv = __builtin_amdgcn_rcpf(s);
        ushort4 a0, a1;
        u16* av0 = reinterpret_cast<u16*>(&a0);
        u16* av1 = reinterpret_cast<u16*>(&a1);
#pragma unroll
        for (int r = 0; r < 4; ++r) { av0[r] = f2bf(e0[r] * inv); av1[r] = f2bf(e1[r] * inv); }
        *reinterpret_cast<ushort4*>(aout + (size_t)m * 32 + lk * 4)      = a0;
        *reinterpret_cast<ushort4*>(aout + (size_t)m * 32 + 16 + lk * 4) = a1;
    }
}

// ---------------- decoder: 2-buffer counted-vmcnt MFMA GRU (swapped) ----------------
template<int RF>
__global__ __launch_bounds__(256, 4) void dec_tile(
    const u16* __restrict__ Hin, const u16* __restrict__ aB,
    const u16* __restrict__ Wh, const u16* __restrict__ Wi,
    const float* __restrict__ dbh, const float* __restrict__ dbi,
    u16* __restrict__ Hout)
{
    constexpr int BM = RF * 32;
    constexpr int NCA = BM / 64;
    constexpr int NS = 16;                 // K stages (512/32)
    __shared__ alignas(16) u16 Als[2][BM * 32];
    __shared__ alignas(16) u16 Bls[2][192 * 32];
    const int tid  = threadIdx.x;
    const int lane = tid & 63;
    const int wid  = tid >> 6;
    const int wr = wid >> 1, wc = wid & 1;
    const int lr = lane & 15, lk = lane >> 4;
    const int m0 = blockIdx.x * BM;
    const int c0 = blockIdx.y * 64;      // within 1024

    size_t a_goff[NCA]; int a_loff[NCA];
#pragma unroll
    for (int j = 0; j < NCA; ++j) {
        int a = wid * NCA + j;
        int r_ = a * 16 + (lane >> 2);
        int kps = (lane & 3) ^ ((r_ >> 1) & 3);
        a_goff[j] = (size_t)(m0 + r_) * 512 + kps * 8;
        a_loff[j] = a * 512 + lane * 8;
    }
    size_t b_goff[3]; int b_loff[3];
#pragma unroll
    for (int j = 0; j < 3; ++j) {
        int b = wid * 3 + j;
        int rr = b * 16 + (lane >> 2);
        int kps = (lane & 3) ^ ((rr >> 1) & 3);
        int grow = (rr >> 6) * 1024 + c0 + (rr & 63);
        b_goff[j] = (size_t)grow * 512 + kps * 8;
        b_loff[j] = b * 512 + lane * 8;
    }
    int a_roff[RF];
#pragma unroll
    for (int i = 0; i < RF; ++i) {
        int row = wr * (RF * 16) + i * 16 + lr;
        a_roff[i] = row * 32 + (lk ^ ((row >> 1) & 3)) * 8;
    }
    int b_roff[3][2];
#pragma unroll
    for (int s = 0; s < 3; ++s)
#pragma unroll
        for (int cf = 0; cf < 2; ++cf) {
            int row = s * 64 + wc * 32 + cf * 16 + lr;
            b_roff[s][cf] = row * 32 + (lk ^ ((row >> 1) & 3)) * 8;
        }

    f32x4 acc[4][2][RF];
#pragma unroll
    for (int s = 0; s < 4; ++s)
#pragma unroll
        for (int cf = 0; cf < 2; ++cf)
#pragma unroll
            for (int i = 0; i < RF; ++i) acc[s][cf][i] = (f32x4){0.f, 0.f, 0.f, 0.f};

    auto issue = [&](int stg) {
        const int buf = stg & 1;
        const int nk = stg * 32;
#pragma unroll
        for (int j = 0; j < NCA; ++j) gload16(Hin + a_goff[j] + nk, &Als[buf][a_loff[j]]);
#pragma unroll
        for (int j = 0; j < 3; ++j) gload16(Wh + b_goff[j] + nk, &Bls[buf][b_loff[j]]);
    };
    auto compute = [&](int buf) {
        short8 a[RF];
#pragma unroll
        for (int i = 0; i < RF; ++i)
            a[i] = *reinterpret_cast<const short8*>(&Als[buf][a_roff[i]]);
#pragma unroll
        for (int s = 0; s < 3; ++s)
#pragma unroll
            for (int cf = 0; cf < 2; ++cf) {
                short8 b = *reinterpret_cast<const short8*>(&Bls[buf][b_roff[s][cf]]);
#pragma unroll
                for (int i = 0; i < RF; ++i)   // SWAPPED: weights first
                    acc[s][cf][i] = __builtin_amdgcn_mfma_f32_16x16x32_bf16(b, a[i], acc[s][cf][i], 0, 0, 0);
            }
    };

    issue(0);
    for (int t = 0; t < NS; ++t) {
        __builtin_amdgcn_s_barrier();
        if (t + 1 < NS) issue(t + 1);
        if constexpr (RF == 4) WAITV(5); else WAITV(4);
        compute(t & 1);
    }

    // rank-32 input-gate contribution (swapped)
#pragma unroll
    for (int i = 0; i < RF; ++i) {
        short8 aw = *reinterpret_cast<const short8*>(
            aB + (size_t)(m0 + wr * (RF * 16) + i * 16 + lr) * 32 + lk * 8);
#pragma unroll
        for (int s = 0; s < 3; ++s) {
            const int d = (s == 2) ? 3 : s;
#pragma unroll
            for (int cf = 0; cf < 2; ++cf) {
                short8 b = *reinterpret_cast<const short8*>(
                    Wi + (size_t)(s * 1024 + c0 + wc * 32 + cf * 16 + lr) * 32 + lk * 8);
                acc[d][cf][i] = __builtin_amdgcn_mfma_f32_16x16x32_bf16(b, aw, acc[d][cf][i], 0, 0, 0);
            }
        }
    }

    // ---- epilogue: lane owns 4 consecutive c for one m ----
    float4 br4[2], bz4[2], bin4[2], bhn4[2];
    int cb[2];
#pragma unroll
    for (int cf = 0; cf < 2; ++cf) {
        cb[cf] = c0 + wc * 32 + cf * 16 + lk * 4;
        float4 h0 = *reinterpret_cast<const float4*>(dbh + cb[cf]);
        float4 i0 = *reinterpret_cast<const float4*>(dbi + cb[cf]);
        float4 h1 = *reinterpret_cast<const float4*>(dbh + 1024 + cb[cf]);
        float4 i1 = *reinterpret_cast<const float4*>(dbi + 1024 + cb[cf]);
        br4[cf] = make_float4(h0.x + i0.x, h0.y + i0.y, h0.z + i0.z, h0.w + i0.w);
        bz4[cf] = make_float4(h1.x + i1.x, h1.y + i1.y, h1.z + i1.z, h1.w + i1.w);
        bin4[cf] = *reinterpret_cast<const float4*>(dbi + 2048 + cb[cf]);
        bhn4[cf] = *reinterpret_cast<const float4*>(dbh + 2048 + cb[cf]);
    }
#pragma unroll
    for (int i = 0; i < RF; ++i) {
        int m = m0 + wr * (RF * 16) + i * 16 + lr;
#pragma unroll
        for (int cf = 0; cf < 2; ++cf) {
            ushort4 hid4 = *reinterpret_cast<const ushort4*>(Hin + (size_t)m * 512 + (cb[cf] & 511));
            const float b_r[4] = {br4[cf].x, br4[cf].y, br4[cf].z, br4[cf].w};
            const float b_z[4] = {bz4[cf].x, bz4[cf].y, bz4[cf].z, bz4[cf].w};
            const float b_in[4] = {bin4[cf].x, bin4[cf].y, bin4[cf].z, bin4[cf].w};
            const float b_hn[4] = {bhn4[cf].x, bhn4[cf].y, bhn4[cf].z, bhn4[cf].w};
            const u16 hv[4] = {hid4.x, hid4.y, hid4.z, hid4.w};
            ushort4 outv;
            u16* ov = reinterpret_cast<u16*>(&outv);
#pragma unroll
            for (int r = 0; r < 4; ++r) {
                float rr_ = fsig(acc[0][cf][i][r] + b_r[r]);
                float zz  = fsig(acc[1][cf][i][r] + b_z[r]);
                float nn  = ftanh(acc[3][cf][i][r] + b_in[r] + rr_ * (acc[2][cf][i][r] + b_hn[r]));
                ov[r] = f2bf((1.0f - zz) * nn + zz * bf2f(hv[r]));
            }
            *reinterpret_cast<ushort4*>(Hout + (size_t)m * 1024 + cb[cf]) = outv;
        }
    }
}

extern "C" void kernel_launch(void* const* d_in, const int* in_sizes, int n_in,
                              void* d_out, int out_size, void* d_ws, size_t ws_size,
                              hipStream_t stream) {
    const int*   symbols = (const int*)  d_in[0];
    const float* eps     = (const float*)d_in[1];
    const float* ewi     = (const float*)d_in[2];
    const float* ebi     = (const float*)d_in[3];
    const float* ewh     = (const float*)d_in[4];
    const float* ebh     = (const float*)d_in[5];
    const float* h2mu_w  = (const float*)d_in[6];
    const float* h2mu_b  = (const float*)d_in[7];
    const float* h2lv_w  = (const float*)d_in[8];
    const float* h2lv_b  = (const float*)d_in[9];
    const float* z2h_w   = (const float*)d_in[10];
    const float* z2h_b   = (const float*)d_in[11];
    const float* h2o_w   = (const float*)d_in[12];
    const float* h2o_b   = (const float*)d_in[13];
    const float* dwi     = (const float*)d_in[14];
    const float* dbi     = (const float*)d_in[15];
    const float* dwh     = (const float*)d_in[16];
    const float* dbh     = (const float*)d_in[17];

    float* out    = (float*)d_out;
    float* out_mu = out;
    float* out_lv = out + 256 * 128;
    float* out_pr = out + 2 * 256 * 128;

    // ---- workspace layout (~34.6 MB) ----
    u16* bufL  = (u16*)d_ws;                            // 16384*512
    u16* bufS  = bufL  + (size_t)16384 * 512;           //  8192*512
    u16* ewh_b = bufS  + (size_t)8192 * 512;            // 1536*1024
    u16* dwh_b = ewh_b + (size_t)1536 * 1024;           // 3072*512
    u16* dwi_b = dwh_b + (size_t)3072 * 512;            // 3072*32
    u16* ewi_b = dwi_b + (size_t)3072 * 32;             // 1536*32
    u16* wo_b  = ewi_b + (size_t)1536 * 32;             // 32*512
    u16* ltab  = wo_b  + (size_t)32 * 512;              // 32*512
    u16* oneh  = ltab  + (size_t)32 * 512;              // 32512*32
    u16* aBuf  = oneh  + (size_t)32512 * 32;            // 8192*32
    float* zlat = (float*)(aBuf + (size_t)8192 * 32);   // 256*128 f32

    // ---- single merged prep launch ----
    prep<<<(4366336 + 255) / 256, 256, 0, stream>>>(
        ewh, dwh, dwi, ewi, h2o_w, symbols, ebi, ebh,
        ewh_b, dwh_b, dwi_b, ewi_b, wo_b, oneh, ltab);

    // ---- encoder ---- d=5 fused with leaf (reads tab directly), writes bufS
    enc_tile<4, true><<<dim3(64, 8), 256, 0, stream>>>(
        nullptr, ewh_b, oneh, ewi_b, ltab, symbols, ebi, ebh, bufS, 5, 31);
    const u16* src = bufS;
    u16*       dst = bufL;
    for (int d = 4; d >= 0; --d) {
        int M = 256 << d;
        if (M >= 4096)
            enc_tile<4, false><<<dim3(M / 128, 8), 256, 0, stream>>>(
                src, ewh_b, oneh, ewi_b, ltab, symbols, ebi, ebh, dst, d, (1 << d) - 1);
        else
            enc_tile<2, false><<<dim3(M / 64, 8), 256, 0, stream>>>(
                src, ewh_b, oneh, ewi_b, ltab, symbols, ebi, ebh, dst, d, (1 << d) - 1);
        const u16* t = src; src = dst; dst = (u16*)t;
    }
    // root in bufL
    mid1<<<256, 256, 0, stream>>>(src, h2mu_w, h2mu_b, h2lv_w, h2lv_b, eps, zlat, out_mu, out_lv);
    mid2<<<256, 512, 0, stream>>>(zlat, z2h_w, z2h_b, bufL);   // hidden0 -> bufL

    // ---- decoder ---- parity: d4 fills bufS exactly, d5 fills bufL exactly
    const u16* hsrc = bufL;
    u16*       hdst = bufS;
    for (int d = 0; d < 6; ++d) {
        int M = 256 << d;
        pred_mfma<<<M / 64, 256, 0, stream>>>(hsrc, wo_b, h2o_b, aBuf, out_pr, d, (1 << d) - 1, 1);
        if (M >= 4096)
            dec_tile<4><<<dim3(M / 128, 16), 256, 0, stream>>>(hsrc, aBuf, dwh_b, dwi_b, dbh, dbi, hdst);
        else
            dec_tile<2><<<dim3(M / 64, 16), 256, 0, stream>>>(hsrc, aBuf, dwh_b, dwi_b, dbh, dbi, hdst);
        const u16* t = hsrc; hsrc = hdst; hdst = (u16*)t;
    }
    pred_mfma<<<16384 / 64, 256, 0, stream>>>(hsrc, wo_b, h2o_b, aBuf, out_pr, 6, 63, 0);
}

// Round 16
// 348.666 us; speedup vs baseline: 1.2432x; 1.2432x over previous
//
#include <hip/hip_runtime.h>
#include <hip/hip_bf16.h>

typedef unsigned short u16;
typedef unsigned int u32;
typedef __attribute__((ext_vector_type(8))) short short8;   // 8 bf16 = 4 VGPR
typedef __attribute__((ext_vector_type(4))) float f32x4;

#define WAITV(N) asm volatile("s_waitcnt vmcnt(" #N ")" ::: "memory")

__device__ __forceinline__ float sigmoidf_(float x) { return 1.0f / (1.0f + expf(-x)); }
// fast gates: v_exp_f32 + v_rcp_f32 (~1 ulp each)
__device__ __forceinline__ float fsig(float x) {
    return __builtin_amdgcn_rcpf(1.0f + __expf(-x));
}
__device__ __forceinline__ float ftanh(float x) {
    x = fminf(fmaxf(x, -15.0f), 15.0f);
    float t = __expf(2.0f * x);
    return (t - 1.0f) * __builtin_amdgcn_rcpf(t + 1.0f);
}

__device__ __forceinline__ float bf2f(u16 u) {
    union { u32 i; float f; } v; v.i = ((u32)u) << 16; return v.f;
}
__device__ __forceinline__ u16 f2bf(float f) {
    union { float f; u32 i; } v; v.f = f;
    u32 lsb = (v.i >> 16) & 1u;
    v.i += 0x7fffu + lsb;            // RNE
    return (u16)(v.i >> 16);
}

// async 16B global->LDS (hardware DMA; LDS dest = wave base + lane*16, global src per-lane)
__device__ __forceinline__ void gload16(const u16* g, u16* l) {
    __builtin_amdgcn_global_load_lds(
        (const __attribute__((address_space(1))) u32*)g,
        (__attribute__((address_space(3))) u32*)l, 16, 0, 0);
}

// ---------------- merged prep: all weight conversions + one-hot + leaf table ----------------
__global__ __launch_bounds__(256) void prep(
    const float* __restrict__ ewh, const float* __restrict__ dwh,
    const float* __restrict__ dwi, const float* __restrict__ ewi,
    const float* __restrict__ h2o_w, const int* __restrict__ symbols,
    const float* __restrict__ ebi, const float* __restrict__ ebh,
    u16* __restrict__ ewh_b, u16* __restrict__ dwh_b, u16* __restrict__ dwi_b,
    u16* __restrict__ ewi_b, u16* __restrict__ wo_b, u16* __restrict__ oneh,
    u16* __restrict__ ltab)
{
    int idx = blockIdx.x * 256 + threadIdx.x;
    if (idx < 1572864) { ewh_b[idx] = f2bf(ewh[idx]); return; }
    idx -= 1572864;
    if (idx < 1572864) { dwh_b[idx] = f2bf(dwh[idx]); return; }
    idx -= 1572864;
    if (idx < 98304) { dwi_b[idx] = f2bf(dwi[idx]); return; }
    idx -= 98304;
    if (idx < 49152) { ewi_b[idx] = f2bf(ewi[idx]); return; }
    idx -= 49152;
    if (idx < 16384) { wo_b[idx] = f2bf(h2o_w[idx]); return; }
    idx -= 16384;
    if (idx < 1040384) {
        int col = idx & 31, row = idx >> 5;
        oneh[idx] = (col == symbols[row]) ? (u16)0x3F80 : (u16)0;
        return;
    }
    idx -= 1040384;
    if (idx < 16384) {
        int c = idx & 511, sym = idx >> 9;
        float r = sigmoidf_(ewi[c * 32 + sym]          + ebi[c]        + ebh[c]);
        float z = sigmoidf_(ewi[(512 + c) * 32 + sym]  + ebi[512 + c]  + ebh[512 + c]);
        float n = tanhf(    ewi[(1024 + c) * 32 + sym] + ebi[1024 + c] + r * ebh[1024 + c]);
        ltab[idx] = f2bf((1.0f - z) * n);
    }
}

// ---------------- Encoder: 2-buffer drain-0 MFMA GEMM + GRU ----------------
// SWAPPED operands: D[row=c][col=m]; lane holds 4 consecutive c (reg) for one m (lane&15).
// Loop: issue(t+1) -> compute(t) -> vmcnt(0) -> barrier (race-free; round-10 schedule).
template<int RF, bool LEAF>
__global__ __launch_bounds__(256, 2) void enc_tile(
    const u16* __restrict__ A, const u16* __restrict__ W,
    const u16* __restrict__ oneh, const u16* __restrict__ Wi,
    const u16* __restrict__ tab, const int* __restrict__ symbols,
    const float* __restrict__ ebi, const float* __restrict__ ebh,
    u16* __restrict__ hout, int dlog, int node_base)
{
    constexpr int BM = RF * 32;
    constexpr int NCA = BM / 64;
    constexpr int NS = 32;                  // K stages (1024/32)
    __shared__ alignas(16) u16 Als[2][BM * 32];
    __shared__ alignas(16) u16 Bls[2][192 * 32];
    const int tid  = threadIdx.x;
    const int lane = tid & 63;
    const int wid  = tid >> 6;
    const int wr = wid >> 1, wc = wid & 1;
    const int lr = lane & 15, lk = lane >> 4;
    const int m0 = blockIdx.x * BM;
    const int c0 = blockIdx.y * 64;
    const int mask = (1 << dlog) - 1;

    size_t a_goff[NCA]; int a_loff[NCA];
    int symL[NCA], symR[NCA];
#pragma unroll
    for (int j = 0; j < NCA; ++j) {
        int a = wid * NCA + j;
        int r_ = a * 16 + (lane >> 2);
        int kps = (lane & 3) ^ ((r_ >> 1) & 3);
        a_loff[j] = a * 512 + lane * 8;
        if constexpr (LEAF) {
            int rg = m0 + r_;
            int b_ = rg >> dlog, jj = rg & mask;
            int cbase = b_ * 127 + 2 * (node_base + jj) + 1;
            symL[j] = symbols[cbase];
            symR[j] = symbols[cbase + 1];
            a_goff[j] = kps * 8;
        } else {
            a_goff[j] = (size_t)(m0 + r_) * 1024 + kps * 8;
            symL[j] = symR[j] = 0;
        }
    }
    size_t b_goff[3]; int b_loff[3];
#pragma unroll
    for (int j = 0; j < 3; ++j) {
        int b = wid * 3 + j;
        int rr = b * 16 + (lane >> 2);
        int kps = (lane & 3) ^ ((rr >> 1) & 3);
        int grow = (rr >> 6) * 512 + c0 + (rr & 63);
        b_goff[j] = (size_t)grow * 1024 + kps * 8;
        b_loff[j] = b * 512 + lane * 8;
    }
    int a_roff[RF];
#pragma unroll
    for (int i = 0; i < RF; ++i) {
        int row = wr * (RF * 16) + i * 16 + lr;
        a_roff[i] = row * 32 + (lk ^ ((row >> 1) & 3)) * 8;
    }
    int b_roff[3][2];
#pragma unroll
    for (int s = 0; s < 3; ++s)
#pragma unroll
        for (int cf = 0; cf < 2; ++cf) {
            int row = s * 64 + wc * 32 + cf * 16 + lr;
            b_roff[s][cf] = row * 32 + (lk ^ ((row >> 1) & 3)) * 8;
        }

    f32x4 acc[4][2][RF];
#pragma unroll
    for (int s = 0; s < 4; ++s)
#pragma unroll
        for (int cf = 0; cf < 2; ++cf)
#pragma unroll
            for (int i = 0; i < RF; ++i) acc[s][cf][i] = (f32x4){0.f, 0.f, 0.f, 0.f};

    auto issue = [&](int stg) {
        const int buf = stg & 1;
        const int nk = stg * 32;
#pragma unroll
        for (int j = 0; j < NCA; ++j) {
            if constexpr (LEAF) {
                const u16* src = (nk < 512)
                    ? tab + (size_t)symL[j] * 512 + nk + a_goff[j]
                    : tab + (size_t)symR[j] * 512 + (nk - 512) + a_goff[j];
                gload16(src, &Als[buf][a_loff[j]]);
            } else {
                gload16(A + a_goff[j] + nk, &Als[buf][a_loff[j]]);
            }
        }
#pragma unroll
        for (int j = 0; j < 3; ++j) gload16(W + b_goff[j] + nk, &Bls[buf][b_loff[j]]);
    };
    auto compute = [&](int buf) {
        short8 a[RF];
#pragma unroll
        for (int i = 0; i < RF; ++i)
            a[i] = *reinterpret_cast<const short8*>(&Als[buf][a_roff[i]]);
#pragma unroll
        for (int s = 0; s < 3; ++s)
#pragma unroll
            for (int cf = 0; cf < 2; ++cf) {
                short8 b = *reinterpret_cast<const short8*>(&Bls[buf][b_roff[s][cf]]);
#pragma unroll
                for (int i = 0; i < RF; ++i)   // SWAPPED: weights first
                    acc[s][cf][i] = __builtin_amdgcn_mfma_f32_16x16x32_bf16(b, a[i], acc[s][cf][i], 0, 0, 0);
            }
    };

    issue(0);
    WAITV(0);
    __builtin_amdgcn_s_barrier();
    for (int t = 0; t < NS - 1; ++t) {
        issue(t + 1);                       // buf (t+1)&1: consumed in compute(t-1), freed by last barrier
        compute(t & 1);
        WAITV(0);                           // my t+1 loads landed
        __builtin_amdgcn_s_barrier();       // => ALL waves' t+1 loads landed
    }
    compute((NS - 1) & 1);

    // ---- rank-32 one-hot gi contribution (swapped): slot map 0->0, 1->1, 2->3 ----
    {
        short8 oh[RF];
#pragma unroll
        for (int i = 0; i < RF; ++i) {
            int m = m0 + wr * (RF * 16) + i * 16 + lr;
            int b_ = m >> dlog, j_ = m & mask;
            oh[i] = *reinterpret_cast<const short8*>(
                oneh + (size_t)(b_ * 127 + node_base + j_) * 32 + lk * 8);
        }
#pragma unroll
        for (int s = 0; s < 3; ++s) {
            const int d = (s == 2) ? 3 : s;
#pragma unroll
            for (int cf = 0; cf < 2; ++cf) {
                short8 wb = *reinterpret_cast<const short8*>(
                    Wi + (size_t)(s * 512 + c0 + wc * 32 + cf * 16 + lr) * 32 + lk * 8);
#pragma unroll
                for (int i = 0; i < RF; ++i)
                    acc[d][cf][i] = __builtin_amdgcn_mfma_f32_16x16x32_bf16(wb, oh[i], acc[d][cf][i], 0, 0, 0);
            }
        }
    }

    // ---- epilogue: lane owns 4 consecutive c (reg r) for one m = base + lr ----
    float4 ebr4[2], ebz4[2], ebin4[2], ebhn4[2];
    int cb[2];
#pragma unroll
    for (int cf = 0; cf < 2; ++cf) {
        cb[cf] = c0 + wc * 32 + cf * 16 + lk * 4;
        float4 bi0 = *reinterpret_cast<const float4*>(ebi + cb[cf]);
        float4 bh0 = *reinterpret_cast<const float4*>(ebh + cb[cf]);
        float4 bi1 = *reinterpret_cast<const float4*>(ebi + 512 + cb[cf]);
        float4 bh1 = *reinterpret_cast<const float4*>(ebh + 512 + cb[cf]);
        ebr4[cf] = make_float4(bi0.x + bh0.x, bi0.y + bh0.y, bi0.z + bh0.z, bi0.w + bh0.w);
        ebz4[cf] = make_float4(bi1.x + bh1.x, bi1.y + bh1.y, bi1.z + bh1.z, bi1.w + bh1.w);
        ebin4[cf] = *reinterpret_cast<const float4*>(ebi + 1024 + cb[cf]);
        ebhn4[cf] = *reinterpret_cast<const float4*>(ebh + 1024 + cb[cf]);
    }
#pragma unroll
    for (int i = 0; i < RF; ++i) {
        int m = m0 + wr * (RF * 16) + i * 16 + lr;
        int symLm = 0, symRm = 0;
        if constexpr (LEAF) {
            int b_ = m >> dlog, jj = m & mask;
            int cbase_ = b_ * 127 + 2 * (node_base + jj) + 1;
            symLm = symbols[cbase_];
            symRm = symbols[cbase_ + 1];
        }
#pragma unroll
        for (int cf = 0; cf < 2; ++cf) {
            ushort4 hl4, hr4;
            if constexpr (LEAF) {
                hl4 = *reinterpret_cast<const ushort4*>(tab + (size_t)symLm * 512 + cb[cf]);
                hr4 = *reinterpret_cast<const ushort4*>(tab + (size_t)symRm * 512 + cb[cf]);
            } else {
                hl4 = *reinterpret_cast<const ushort4*>(A + (size_t)m * 1024 + cb[cf]);
                hr4 = *reinterpret_cast<const ushort4*>(A + (size_t)m * 1024 + 512 + cb[cf]);
            }
            const float eb_r[4] = {ebr4[cf].x, ebr4[cf].y, ebr4[cf].z, ebr4[cf].w};
            const float eb_z[4] = {ebz4[cf].x, ebz4[cf].y, ebz4[cf].z, ebz4[cf].w};
            const float eb_in[4] = {ebin4[cf].x, ebin4[cf].y, ebin4[cf].z, ebin4[cf].w};
            const float eb_hn[4] = {ebhn4[cf].x, ebhn4[cf].y, ebhn4[cf].z, ebhn4[cf].w};
            const u16 hlv[4] = {hl4.x, hl4.y, hl4.z, hl4.w};
            const u16 hrv[4] = {hr4.x, hr4.y, hr4.z, hr4.w};
            ushort4 outv;
            u16* ov = reinterpret_cast<u16*>(&outv);
#pragma unroll
            for (int r = 0; r < 4; ++r) {
                float rr_ = fsig(acc[0][cf][i][r] + eb_r[r]);
                float zz  = fsig(acc[1][cf][i][r] + eb_z[r]);
                float nn  = ftanh(acc[3][cf][i][r] + eb_in[r] + rr_ * (acc[2][cf][i][r] + eb_hn[r]));
                float hm = (bf2f(hlv[r]) + bf2f(hrv[r])) * 0.5f;
                ov[r] = f2bf((1.0f - zz) * nn + zz * hm);
            }
            *reinterpret_cast<ushort4*>(hout + (size_t)m * 512 + cb[cf]) = outv;
        }
    }
}

// ---------------- mid: mu/logvar/zlat ----------------
__global__ __launch_bounds__(256) void mid1(
    const u16* __restrict__ root, const float* __restrict__ h2mu_w,
    const float* __restrict__ h2mu_b, const float* __restrict__ h2lv_w,
    const float* __restrict__ h2lv_b, const float* __restrict__ eps,
    float* __restrict__ zlat, float* __restrict__ out_mu,
    float* __restrict__ out_lv)
{
    int b = blockIdx.x, t = threadIdx.x;
    __shared__ float rs[512];
    rs[t]       = bf2f(root[(size_t)b * 512 + t]);
    rs[t + 256] = bf2f(root[(size_t)b * 512 + t + 256]);
    __syncthreads();
    const float* w = (t < 128) ? (h2mu_w + (size_t)t * 512) : (h2lv_w + (size_t)(t - 128) * 512);
    float acc = 0.0f;
    for (int k = 0; k < 512; ++k) acc += rs[k] * w[k];
    acc += (t < 128) ? h2mu_b[t] : h2lv_b[t - 128];
    __shared__ float vals[256];
    vals[t] = acc;
    __syncthreads();
    if (t < 128) {
        float mu = vals[t], lv = vals[t + 128];
        float zl = mu + eps[b * 128 + t] * expf(0.5f * lv);
        zlat[b * 128 + t] = zl;
        out_mu[b * 128 + t] = mu;
        out_lv[b * 128 + t] = lv;
    }
}

__global__ __launch_bounds__(512) void mid2(
    const float* __restrict__ zlat, const float* __restrict__ z2h_w,
    const float* __restrict__ z2h_b, u16* __restrict__ hidden)
{
    int b = blockIdx.x, t = threadIdx.x;
    __shared__ float zs[128];
    if (t < 128) zs[t] = zlat[b * 128 + t];
    __syncthreads();
    float acc = z2h_b[t];
    for (int k = 0; k < 128; ++k) acc += zs[k] * z2h_w[(size_t)t * 128 + k];
    hidden[(size_t)b * 512 + t] = f2bf(acc);
}

// ---------------- decoder pred via swapped MFMA + softmax over lk-groups ----------------
__global__ __launch_bounds__(256) void pred_mfma(
    const u16* __restrict__ hidden, const u16* __restrict__ Wo,
    const float* __restrict__ h2o_b, u16* __restrict__ aout,
    float* __restrict__ preds_out, int dlog, int node_base, int write_a)
{
    const int lane = threadIdx.x & 63;
    const int wid  = threadIdx.x >> 6;
    const int lr = lane & 15, lk = lane >> 4;
    const int m0 = blockIdx.x * 64 + wid * 16;

    f32x4 acc0 = (f32x4){0.f, 0.f, 0.f, 0.f};
    f32x4 acc1 = (f32x4){0.f, 0.f, 0.f, 0.f};
    const u16* Arow = hidden + (size_t)(m0 + lr) * 512 + lk * 8;
    const u16* B0 = Wo + (size_t)lr * 512 + lk * 8;
    const u16* B1 = Wo + (size_t)(16 + lr) * 512 + lk * 8;
#pragma unroll
    for (int k0 = 0; k0 < 512; k0 += 32) {
        short8 a  = *reinterpret_cast<const short8*>(Arow + k0);
        short8 b0 = *reinterpret_cast<const short8*>(B0 + k0);
        short8 b1 = *reinterpret_cast<const short8*>(B1 + k0);
        acc0 = __builtin_amdgcn_mfma_f32_16x16x32_bf16(b0, a, acc0, 0, 0, 0);
        acc1 = __builtin_amdgcn_mfma_f32_16x16x32_bf16(b1, a, acc1, 0, 0, 0);
    }
    float4 bb0 = *reinterpret_cast<const float4*>(h2o_b + lk * 4);
    float4 bb1 = *reinterpret_cast<const float4*>(h2o_b + 16 + lk * 4);
    float p0[4], p1[4];
    p0[0] = acc0[0] + bb0.x; p0[1] = acc0[1] + bb0.y; p0[2] = acc0[2] + bb0.z; p0[3] = acc0[3] + bb0.w;
    p1[0] = acc1[0] + bb1.x; p1[1] = acc1[1] + bb1.y; p1[2] = acc1[2] + bb1.z; p1[3] = acc1[3] + bb1.w;
    float mx = fmaxf(fmaxf(fmaxf(p0[0], p0[1]), fmaxf(p0[2], p0[3])),
                     fmaxf(fmaxf(p1[0], p1[1]), fmaxf(p1[2], p1[3])));
    mx = fmaxf(mx, __shfl_xor(mx, 16));
    mx = fmaxf(mx, __shfl_xor(mx, 32));
    float e0[4], e1[4], s = 0.0f;
#pragma unroll
    for (int r = 0; r < 4; ++r) { e0[r] = __expf(p0[r] - mx); e1[r] = __expf(p1[r] - mx); s += e0[r] + e1[r]; }
    s += __shfl_xor(s, 16);
    s += __shfl_xor(s, 32);

    int m = m0 + lr;
    int b_ = m >> dlog, j_ = m & ((1 << dlog) - 1);
    size_t o = (size_t)(b_ * 127 + node_base + j_) * 32;
    *reinterpret_cast<float4*>(preds_out + o + lk * 4)      = make_float4(p0[0], p0[1], p0[2], p0[3]);
    *reinterpret_cast<float4*>(preds_out + o + 16 + lk * 4) = make_float4(p1[0], p1[1], p1[2], p1[3]);
    if (write_a) {
        float inv = __builtin_amdgcn_rcpf(s);
        ushort4 a0, a1;
        u16* av0 = reinterpret_cast<u16*>(&a0);
        u16* av1 = reinterpret_cast<u16*>(&a1);
#pragma unroll
        for (int r = 0; r < 4; ++r) { av0[r] = f2bf(e0[r] * inv); av1[r] = f2bf(e1[r] * inv); }
        *reinterpret_cast<ushort4*>(aout + (size_t)m * 32 + lk * 4)      = a0;
        *reinterpret_cast<ushort4*>(aout + (size_t)m * 32 + 16 + lk * 4) = a1;
    }
}

// ---------------- decoder: 2-buffer drain-0 MFMA GRU (swapped) ----------------
template<int RF>
__global__ __launch_bounds__(256, 2) void dec_tile(
    const u16* __restrict__ Hin, const u16* __restrict__ aB,
    const u16* __restrict__ Wh, const u16* __restrict__ Wi,
    const float* __restrict__ dbh, const float* __restrict__ dbi,
    u16* __restrict__ Hout)
{
    constexpr int BM = RF * 32;
    constexpr int NCA = BM / 64;
    constexpr int NS = 16;                 // K stages (512/32)
    __shared__ alignas(16) u16 Als[2][BM * 32];
    __shared__ alignas(16) u16 Bls[2][192 * 32];
    const int tid  = threadIdx.x;
    const int lane = tid & 63;
    const int wid  = tid >> 6;
    const int wr = wid >> 1, wc = wid & 1;
    const int lr = lane & 15, lk = lane >> 4;
    const int m0 = blockIdx.x * BM;
    const int c0 = blockIdx.y * 64;      // within 1024

    size_t a_goff[NCA]; int a_loff[NCA];
#pragma unroll
    for (int j = 0; j < NCA; ++j) {
        int a = wid * NCA + j;
        int r_ = a * 16 + (lane >> 2);
        int kps = (lane & 3) ^ ((r_ >> 1) & 3);
        a_goff[j] = (size_t)(m0 + r_) * 512 + kps * 8;
        a_loff[j] = a * 512 + lane * 8;
    }
    size_t b_goff[3]; int b_loff[3];
#pragma unroll
    for (int j = 0; j < 3; ++j) {
        int b = wid * 3 + j;
        int rr = b * 16 + (lane >> 2);
        int kps = (lane & 3) ^ ((rr >> 1) & 3);
        int grow = (rr >> 6) * 1024 + c0 + (rr & 63);
        b_goff[j] = (size_t)grow * 512 + kps * 8;
        b_loff[j] = b * 512 + lane * 8;
    }
    int a_roff[RF];
#pragma unroll
    for (int i = 0; i < RF; ++i) {
        int row = wr * (RF * 16) + i * 16 + lr;
        a_roff[i] = row * 32 + (lk ^ ((row >> 1) & 3)) * 8;
    }
    int b_roff[3][2];
#pragma unroll
    for (int s = 0; s < 3; ++s)
#pragma unroll
        for (int cf = 0; cf < 2; ++cf) {
            int row = s * 64 + wc * 32 + cf * 16 + lr;
            b_roff[s][cf] = row * 32 + (lk ^ ((row >> 1) & 3)) * 8;
        }

    f32x4 acc[4][2][RF];
#pragma unroll
    for (int s = 0; s < 4; ++s)
#pragma unroll
        for (int cf = 0; cf < 2; ++cf)
#pragma unroll
            for (int i = 0; i < RF; ++i) acc[s][cf][i] = (f32x4){0.f, 0.f, 0.f, 0.f};

    auto issue = [&](int stg) {
        const int buf = stg & 1;
        const int nk = stg * 32;
#pragma unroll
        for (int j = 0; j < NCA; ++j) gload16(Hin + a_goff[j] + nk, &Als[buf][a_loff[j]]);
#pragma unroll
        for (int j = 0; j < 3; ++j) gload16(Wh + b_goff[j] + nk, &Bls[buf][b_loff[j]]);
    };
    auto compute = [&](int buf) {
        short8 a[RF];
#pragma unroll
        for (int i = 0; i < RF; ++i)
            a[i] = *reinterpret_cast<const short8*>(&Als[buf][a_roff[i]]);
#pragma unroll
        for (int s = 0; s < 3; ++s)
#pragma unroll
            for (int cf = 0; cf < 2; ++cf) {
                short8 b = *reinterpret_cast<const short8*>(&Bls[buf][b_roff[s][cf]]);
#pragma unroll
                for (int i = 0; i < RF; ++i)   // SWAPPED: weights first
                    acc[s][cf][i] = __builtin_amdgcn_mfma_f32_16x16x32_bf16(b, a[i], acc[s][cf][i], 0, 0, 0);
            }
    };

    issue(0);
    WAITV(0);
    __builtin_amdgcn_s_barrier();
    for (int t = 0; t < NS - 1; ++t) {
        issue(t + 1);
        compute(t & 1);
        WAITV(0);
        __builtin_amdgcn_s_barrier();
    }
    compute((NS - 1) & 1);

    // rank-32 input-gate contribution (swapped)
#pragma unroll
    for (int i = 0; i < RF; ++i) {
        short8 aw = *reinterpret_cast<const short8*>(
            aB + (size_t)(m0 + wr * (RF * 16) + i * 16 + lr) * 32 + lk * 8);
#pragma unroll
        for (int s = 0; s < 3; ++s) {
            const int d = (s == 2) ? 3 : s;
#pragma unroll
            for (int cf = 0; cf < 2; ++cf) {
                short8 b = *reinterpret_cast<const short8*>(
                    Wi + (size_t)(s * 1024 + c0 + wc * 32 + cf * 16 + lr) * 32 + lk * 8);
                acc[d][cf][i] = __builtin_amdgcn_mfma_f32_16x16x32_bf16(b, aw, acc[d][cf][i], 0, 0, 0);
            }
        }
    }

    // ---- epilogue: lane owns 4 consecutive c for one m ----
    float4 br4[2], bz4[2], bin4[2], bhn4[2];
    int cb[2];
#pragma unroll
    for (int cf = 0; cf < 2; ++cf) {
        cb[cf] = c0 + wc * 32 + cf * 16 + lk * 4;
        float4 h0 = *reinterpret_cast<const float4*>(dbh + cb[cf]);
        float4 i0 = *reinterpret_cast<const float4*>(dbi + cb[cf]);
        float4 h1 = *reinterpret_cast<const float4*>(dbh + 1024 + cb[cf]);
        float4 i1 = *reinterpret_cast<const float4*>(dbi + 1024 + cb[cf]);
        br4[cf] = make_float4(h0.x + i0.x, h0.y + i0.y, h0.z + i0.z, h0.w + i0.w);
        bz4[cf] = make_float4(h1.x + i1.x, h1.y + i1.y, h1.z + i1.z, h1.w + i1.w);
        bin4[cf] = *reinterpret_cast<const float4*>(dbi + 2048 + cb[cf]);
        bhn4[cf] = *reinterpret_cast<const float4*>(dbh + 2048 + cb[cf]);
    }
#pragma unroll
    for (int i = 0; i < RF; ++i) {
        int m = m0 + wr * (RF * 16) + i * 16 + lr;
#pragma unroll
        for (int cf = 0; cf < 2; ++cf) {
            ushort4 hid4 = *reinterpret_cast<const ushort4*>(Hin + (size_t)m * 512 + (cb[cf] & 511));
            const float b_r[4] = {br4[cf].x, br4[cf].y, br4[cf].z, br4[cf].w};
            const float b_z[4] = {bz4[cf].x, bz4[cf].y, bz4[cf].z, bz4[cf].w};
            const float b_in[4] = {bin4[cf].x, bin4[cf].y, bin4[cf].z, bin4[cf].w};
            const float b_hn[4] = {bhn4[cf].x, bhn4[cf].y, bhn4[cf].z, bhn4[cf].w};
            const u16 hv[4] = {hid4.x, hid4.y, hid4.z, hid4.w};
            ushort4 outv;
            u16* ov = reinterpret_cast<u16*>(&outv);
#pragma unroll
            for (int r = 0; r < 4; ++r) {
                float rr_ = fsig(acc[0][cf][i][r] + b_r[r]);
                float zz  = fsig(acc[1][cf][i][r] + b_z[r]);
                float nn  = ftanh(acc[3][cf][i][r] + b_in[r] + rr_ * (acc[2][cf][i][r] + b_hn[r]));
                ov[r] = f2bf((1.0f - zz) * nn + zz * bf2f(hv[r]));
            }
            *reinterpret_cast<ushort4*>(Hout + (size_t)m * 1024 + cb[cf]) = outv;
        }
    }
}

extern "C" void kernel_launch(void* const* d_in, const int* in_sizes, int n_in,
                              void* d_out, int out_size, void* d_ws, size_t ws_size,
                              hipStream_t stream) {
    const int*   symbols = (const int*)  d_in[0];
    const float* eps     = (const float*)d_in[1];
    const float* ewi     = (const float*)d_in[2];
    const float* ebi     = (const float*)d_in[3];
    const float* ewh     = (const float*)d_in[4];
    const float* ebh     = (const float*)d_in[5];
    const float* h2mu_w  = (const float*)d_in[6];
    const float* h2mu_b  = (const float*)d_in[7];
    const float* h2lv_w  = (const float*)d_in[8];
    const float* h2lv_b  = (const float*)d_in[9];
    const float* z2h_w   = (const float*)d_in[10];
    const float* z2h_b   = (const float*)d_in[11];
    const float* h2o_w   = (const float*)d_in[12];
    const float* h2o_b   = (const float*)d_in[13];
    const float* dwi     = (const float*)d_in[14];
    const float* dbi     = (const float*)d_in[15];
    const float* dwh     = (const float*)d_in[16];
    const float* dbh     = (const float*)d_in[17];

    float* out    = (float*)d_out;
    float* out_mu = out;
    float* out_lv = out + 256 * 128;
    float* out_pr = out + 2 * 256 * 128;

    // ---- workspace layout (~34.6 MB) ----
    u16* bufL  = (u16*)d_ws;                            // 16384*512
    u16* bufS  = bufL  + (size_t)16384 * 512;           //  8192*512
    u16* ewh_b = bufS  + (size_t)8192 * 512;            // 1536*1024
    u16* dwh_b = ewh_b + (size_t)1536 * 1024;           // 3072*512
    u16* dwi_b = dwh_b + (size_t)3072 * 512;            // 3072*32
    u16* ewi_b = dwi_b + (size_t)3072 * 32;             // 1536*32
    u16* wo_b  = ewi_b + (size_t)1536 * 32;             // 32*512
    u16* ltab  = wo_b  + (size_t)32 * 512;              // 32*512
    u16* oneh  = ltab  + (size_t)32 * 512;              // 32512*32
    u16* aBuf  = oneh  + (size_t)32512 * 32;            // 8192*32
    float* zlat = (float*)(aBuf + (size_t)8192 * 32);   // 256*128 f32

    // ---- single merged prep launch ----
    prep<<<(4366336 + 255) / 256, 256, 0, stream>>>(
        ewh, dwh, dwi, ewi, h2o_w, symbols, ebi, ebh,
        ewh_b, dwh_b, dwi_b, ewi_b, wo_b, oneh, ltab);

    // ---- encoder ---- d=5 fused with leaf (reads tab directly), writes bufS
    enc_tile<4, true><<<dim3(64, 8), 256, 0, stream>>>(
        nullptr, ewh_b, oneh, ewi_b, ltab, symbols, ebi, ebh, bufS, 5, 31);
    const u16* src = bufS;
    u16*       dst = bufL;
    for (int d = 4; d >= 0; --d) {
        int M = 256 << d;
        if (M >= 4096)
            enc_tile<4, false><<<dim3(M / 128, 8), 256, 0, stream>>>(
                src, ewh_b, oneh, ewi_b, ltab, symbols, ebi, ebh, dst, d, (1 << d) - 1);
        else
            enc_tile<2, false><<<dim3(M / 64, 8), 256, 0, stream>>>(
                src, ewh_b, oneh, ewi_b, ltab, symbols, ebi, ebh, dst, d, (1 << d) - 1);
        const u16* t = src; src = dst; dst = (u16*)t;
    }
    // root in bufL
    mid1<<<256, 256, 0, stream>>>(src, h2mu_w, h2mu_b, h2lv_w, h2lv_b, eps, zlat, out_mu, out_lv);
    mid2<<<256, 512, 0, stream>>>(zlat, z2h_w, z2h_b, bufL);   // hidden0 -> bufL

    // ---- decoder ---- parity: d4 fills bufS exactly, d5 fills bufL exactly
    const u16* hsrc = bufL;
    u16*       hdst = bufS;
    for (int d = 0; d < 6; ++d) {
        int M = 256 << d;
        pred_mfma<<<M / 64, 256, 0, stream>>>(hsrc, wo_b, h2o_b, aBuf, out_pr, d, (1 << d) - 1, 1);
        if (M >= 4096)
            dec_tile<4><<<dim3(M / 128, 16), 256, 0, stream>>>(hsrc, aBuf, dwh_b, dwi_b, dbh, dbi, hdst);
        else
            dec_tile<2><<<dim3(M / 64, 16), 256, 0, stream>>>(hsrc, aBuf, dwh_b, dwi_b, dbh, dbi, hdst);
        const u16* t = hsrc; hsrc = hdst; hdst = (u16*)t;
    }
    pred_mfma<<<16384 / 64, 256, 0, stream>>>(hsrc, wo_b, h2o_b, aBuf, out_pr, 6, 63, 0);
}

// Round 17
// 347.780 us; speedup vs baseline: 1.2464x; 1.0025x over previous
//
#include <hip/hip_runtime.h>
#include <hip/hip_bf16.h>

typedef unsigned short u16;
typedef unsigned int u32;
typedef __attribute__((ext_vector_type(8))) short short8;   // 8 bf16 = 4 VGPR
typedef __attribute__((ext_vector_type(4))) float f32x4;

#define WAITV(N) asm volatile("s_waitcnt vmcnt(" #N ")" ::: "memory")

__device__ __forceinline__ float sigmoidf_(float x) { return 1.0f / (1.0f + expf(-x)); }
__device__ __forceinline__ float fsig(float x) {
    return __builtin_amdgcn_rcpf(1.0f + __expf(-x));
}
__device__ __forceinline__ float ftanh(float x) {
    x = fminf(fmaxf(x, -15.0f), 15.0f);
    float t = __expf(2.0f * x);
    return (t - 1.0f) * __builtin_amdgcn_rcpf(t + 1.0f);
}

__device__ __forceinline__ float bf2f(u16 u) {
    union { u32 i; float f; } v; v.i = ((u32)u) << 16; return v.f;
}
__device__ __forceinline__ u16 f2bf(float f) {
    union { float f; u32 i; } v; v.f = f;
    u32 lsb = (v.i >> 16) & 1u;
    v.i += 0x7fffu + lsb;            // RNE
    return (u16)(v.i >> 16);
}

__device__ __forceinline__ void gload16(const u16* g, u16* l) {
    __builtin_amdgcn_global_load_lds(
        (const __attribute__((address_space(1))) u32*)g,
        (__attribute__((address_space(3))) u32*)l, 16, 0, 0);
}

// ---------------- merged prep ----------------
__global__ __launch_bounds__(256) void prep(
    const float* __restrict__ ewh, const float* __restrict__ dwh,
    const float* __restrict__ dwi, const float* __restrict__ ewi,
    const float* __restrict__ h2o_w, const int* __restrict__ symbols,
    const float* __restrict__ ebi, const float* __restrict__ ebh,
    u16* __restrict__ ewh_b, u16* __restrict__ dwh_b, u16* __restrict__ dwi_b,
    u16* __restrict__ ewi_b, u16* __restrict__ wo_b, u16* __restrict__ oneh,
    u16* __restrict__ ltab)
{
    int idx = blockIdx.x * 256 + threadIdx.x;
    if (idx < 1572864) { ewh_b[idx] = f2bf(ewh[idx]); return; }
    idx -= 1572864;
    if (idx < 1572864) { dwh_b[idx] = f2bf(dwh[idx]); return; }
    idx -= 1572864;
    if (idx < 98304) { dwi_b[idx] = f2bf(dwi[idx]); return; }
    idx -= 98304;
    if (idx < 49152) { ewi_b[idx] = f2bf(ewi[idx]); return; }
    idx -= 49152;
    if (idx < 16384) { wo_b[idx] = f2bf(h2o_w[idx]); return; }
    idx -= 16384;
    if (idx < 1040384) {
        int col = idx & 31, row = idx >> 5;
        oneh[idx] = (col == symbols[row]) ? (u16)0x3F80 : (u16)0;
        return;
    }
    idx -= 1040384;
    if (idx < 16384) {
        int c = idx & 511, sym = idx >> 9;
        float r = sigmoidf_(ewi[c * 32 + sym]          + ebi[c]        + ebh[c]);
        float z = sigmoidf_(ewi[(512 + c) * 32 + sym]  + ebi[512 + c]  + ebh[512 + c]);
        float n = tanhf(    ewi[(1024 + c) * 32 + sym] + ebi[1024 + c] + r * ebh[1024 + c]);
        ltab[idx] = f2bf((1.0f - z) * n);
    }
}

// ---------------- Encoder: 2-buffer drain-0 MFMA GEMM + GRU (unchanged from r16) ----------------
template<int RF, bool LEAF>
__global__ __launch_bounds__(256, 2) void enc_tile(
    const u16* __restrict__ A, const u16* __restrict__ W,
    const u16* __restrict__ oneh, const u16* __restrict__ Wi,
    const u16* __restrict__ tab, const int* __restrict__ symbols,
    const float* __restrict__ ebi, const float* __restrict__ ebh,
    u16* __restrict__ hout, int dlog, int node_base)
{
    constexpr int BM = RF * 32;
    constexpr int NCA = BM / 64;
    constexpr int NS = 32;
    __shared__ alignas(16) u16 Als[2][BM * 32];
    __shared__ alignas(16) u16 Bls[2][192 * 32];
    const int tid  = threadIdx.x;
    const int lane = tid & 63;
    const int wid  = tid >> 6;
    const int wr = wid >> 1, wc = wid & 1;
    const int lr = lane & 15, lk = lane >> 4;
    const int m0 = blockIdx.x * BM;
    const int c0 = blockIdx.y * 64;
    const int mask = (1 << dlog) - 1;

    size_t a_goff[NCA]; int a_loff[NCA];
    int symL[NCA], symR[NCA];
#pragma unroll
    for (int j = 0; j < NCA; ++j) {
        int a = wid * NCA + j;
        int r_ = a * 16 + (lane >> 2);
        int kps = (lane & 3) ^ ((r_ >> 1) & 3);
        a_loff[j] = a * 512 + lane * 8;
        if constexpr (LEAF) {
            int rg = m0 + r_;
            int b_ = rg >> dlog, jj = rg & mask;
            int cbase = b_ * 127 + 2 * (node_base + jj) + 1;
            symL[j] = symbols[cbase];
            symR[j] = symbols[cbase + 1];
            a_goff[j] = kps * 8;
        } else {
            a_goff[j] = (size_t)(m0 + r_) * 1024 + kps * 8;
            symL[j] = symR[j] = 0;
        }
    }
    size_t b_goff[3]; int b_loff[3];
#pragma unroll
    for (int j = 0; j < 3; ++j) {
        int b = wid * 3 + j;
        int rr = b * 16 + (lane >> 2);
        int kps = (lane & 3) ^ ((rr >> 1) & 3);
        int grow = (rr >> 6) * 512 + c0 + (rr & 63);
        b_goff[j] = (size_t)grow * 1024 + kps * 8;
        b_loff[j] = b * 512 + lane * 8;
    }
    int a_roff[RF];
#pragma unroll
    for (int i = 0; i < RF; ++i) {
        int row = wr * (RF * 16) + i * 16 + lr;
        a_roff[i] = row * 32 + (lk ^ ((row >> 1) & 3)) * 8;
    }
    int b_roff[3][2];
#pragma unroll
    for (int s = 0; s < 3; ++s)
#pragma unroll
        for (int cf = 0; cf < 2; ++cf) {
            int row = s * 64 + wc * 32 + cf * 16 + lr;
            b_roff[s][cf] = row * 32 + (lk ^ ((row >> 1) & 3)) * 8;
        }

    f32x4 acc[4][2][RF];
#pragma unroll
    for (int s = 0; s < 4; ++s)
#pragma unroll
        for (int cf = 0; cf < 2; ++cf)
#pragma unroll
            for (int i = 0; i < RF; ++i) acc[s][cf][i] = (f32x4){0.f, 0.f, 0.f, 0.f};

    auto issue = [&](int stg) {
        const int buf = stg & 1;
        const int nk = stg * 32;
#pragma unroll
        for (int j = 0; j < NCA; ++j) {
            if constexpr (LEAF) {
                const u16* src = (nk < 512)
                    ? tab + (size_t)symL[j] * 512 + nk + a_goff[j]
                    : tab + (size_t)symR[j] * 512 + (nk - 512) + a_goff[j];
                gload16(src, &Als[buf][a_loff[j]]);
            } else {
                gload16(A + a_goff[j] + nk, &Als[buf][a_loff[j]]);
            }
        }
#pragma unroll
        for (int j = 0; j < 3; ++j) gload16(W + b_goff[j] + nk, &Bls[buf][b_loff[j]]);
    };
    auto compute = [&](int buf) {
        short8 a[RF];
#pragma unroll
        for (int i = 0; i < RF; ++i)
            a[i] = *reinterpret_cast<const short8*>(&Als[buf][a_roff[i]]);
#pragma unroll
        for (int s = 0; s < 3; ++s)
#pragma unroll
            for (int cf = 0; cf < 2; ++cf) {
                short8 b = *reinterpret_cast<const short8*>(&Bls[buf][b_roff[s][cf]]);
#pragma unroll
                for (int i = 0; i < RF; ++i)
                    acc[s][cf][i] = __builtin_amdgcn_mfma_f32_16x16x32_bf16(b, a[i], acc[s][cf][i], 0, 0, 0);
            }
    };

    issue(0);
    WAITV(0);
    __builtin_amdgcn_s_barrier();
    for (int t = 0; t < NS - 1; ++t) {
        issue(t + 1);
        compute(t & 1);
        WAITV(0);
        __builtin_amdgcn_s_barrier();
    }
    compute((NS - 1) & 1);

    {
        short8 oh[RF];
#pragma unroll
        for (int i = 0; i < RF; ++i) {
            int m = m0 + wr * (RF * 16) + i * 16 + lr;
            int b_ = m >> dlog, j_ = m & mask;
            oh[i] = *reinterpret_cast<const short8*>(
                oneh + (size_t)(b_ * 127 + node_base + j_) * 32 + lk * 8);
        }
#pragma unroll
        for (int s = 0; s < 3; ++s) {
            const int d = (s == 2) ? 3 : s;
#pragma unroll
            for (int cf = 0; cf < 2; ++cf) {
                short8 wb = *reinterpret_cast<const short8*>(
                    Wi + (size_t)(s * 512 + c0 + wc * 32 + cf * 16 + lr) * 32 + lk * 8);
#pragma unroll
                for (int i = 0; i < RF; ++i)
                    acc[d][cf][i] = __builtin_amdgcn_mfma_f32_16x16x32_bf16(wb, oh[i], acc[d][cf][i], 0, 0, 0);
            }
        }
    }

    float4 ebr4[2], ebz4[2], ebin4[2], ebhn4[2];
    int cb[2];
#pragma unroll
    for (int cf = 0; cf < 2; ++cf) {
        cb[cf] = c0 + wc * 32 + cf * 16 + lk * 4;
        float4 bi0 = *reinterpret_cast<const float4*>(ebi + cb[cf]);
        float4 bh0 = *reinterpret_cast<const float4*>(ebh + cb[cf]);
        float4 bi1 = *reinterpret_cast<const float4*>(ebi + 512 + cb[cf]);
        float4 bh1 = *reinterpret_cast<const float4*>(ebh + 512 + cb[cf]);
        ebr4[cf] = make_float4(bi0.x + bh0.x, bi0.y + bh0.y, bi0.z + bh0.z, bi0.w + bh0.w);
        ebz4[cf] = make_float4(bi1.x + bh1.x, bi1.y + bh1.y, bi1.z + bh1.z, bi1.w + bh1.w);
        ebin4[cf] = *reinterpret_cast<const float4*>(ebi + 1024 + cb[cf]);
        ebhn4[cf] = *reinterpret_cast<const float4*>(ebh + 1024 + cb[cf]);
    }
#pragma unroll
    for (int i = 0; i < RF; ++i) {
        int m = m0 + wr * (RF * 16) + i * 16 + lr;
        int symLm = 0, symRm = 0;
        if constexpr (LEAF) {
            int b_ = m >> dlog, jj = m & mask;
            int cbase_ = b_ * 127 + 2 * (node_base + jj) + 1;
            symLm = symbols[cbase_];
            symRm = symbols[cbase_ + 1];
        }
#pragma unroll
        for (int cf = 0; cf < 2; ++cf) {
            ushort4 hl4, hr4;
            if constexpr (LEAF) {
                hl4 = *reinterpret_cast<const ushort4*>(tab + (size_t)symLm * 512 + cb[cf]);
                hr4 = *reinterpret_cast<const ushort4*>(tab + (size_t)symRm * 512 + cb[cf]);
            } else {
                hl4 = *reinterpret_cast<const ushort4*>(A + (size_t)m * 1024 + cb[cf]);
                hr4 = *reinterpret_cast<const ushort4*>(A + (size_t)m * 1024 + 512 + cb[cf]);
            }
            const float eb_r[4] = {ebr4[cf].x, ebr4[cf].y, ebr4[cf].z, ebr4[cf].w};
            const float eb_z[4] = {ebz4[cf].x, ebz4[cf].y, ebz4[cf].z, ebz4[cf].w};
            const float eb_in[4] = {ebin4[cf].x, ebin4[cf].y, ebin4[cf].z, ebin4[cf].w};
            const float eb_hn[4] = {ebhn4[cf].x, ebhn4[cf].y, ebhn4[cf].z, ebhn4[cf].w};
            const u16 hlv[4] = {hl4.x, hl4.y, hl4.z, hl4.w};
            const u16 hrv[4] = {hr4.x, hr4.y, hr4.z, hr4.w};
            ushort4 outv;
            u16* ov = reinterpret_cast<u16*>(&outv);
#pragma unroll
            for (int r = 0; r < 4; ++r) {
                float rr_ = fsig(acc[0][cf][i][r] + eb_r[r]);
                float zz  = fsig(acc[1][cf][i][r] + eb_z[r]);
                float nn  = ftanh(acc[3][cf][i][r] + eb_in[r] + rr_ * (acc[2][cf][i][r] + eb_hn[r]));
                float hm = (bf2f(hlv[r]) + bf2f(hrv[r])) * 0.5f;
                ov[r] = f2bf((1.0f - zz) * nn + zz * hm);
            }
            *reinterpret_cast<ushort4*>(hout + (size_t)m * 512 + cb[cf]) = outv;
        }
    }
}

// ---------------- fused mid: mu/logvar/zlat + hidden0 ----------------
__global__ __launch_bounds__(256) void midf(
    const u16* __restrict__ root, const float* __restrict__ h2mu_w,
    const float* __restrict__ h2mu_b, const float* __restrict__ h2lv_w,
    const float* __restrict__ h2lv_b, const float* __restrict__ eps,
    const float* __restrict__ z2h_w, const float* __restrict__ z2h_b,
    float* __restrict__ out_mu, float* __restrict__ out_lv,
    u16* __restrict__ hidden)
{
    int b = blockIdx.x, t = threadIdx.x;
    __shared__ float rs[512];
    __shared__ float zl[128];
    rs[t]       = bf2f(root[(size_t)b * 512 + t]);
    rs[t + 256] = bf2f(root[(size_t)b * 512 + t + 256]);
    __syncthreads();
    const float* w = (t < 128) ? (h2mu_w + (size_t)t * 512) : (h2lv_w + (size_t)(t - 128) * 512);
    float acc = 0.0f;
    for (int k = 0; k < 512; ++k) acc += rs[k] * w[k];
    acc += (t < 128) ? h2mu_b[t] : h2lv_b[t - 128];
    __shared__ float vals[256];
    vals[t] = acc;
    __syncthreads();
    if (t < 128) {
        float mu = vals[t], lv = vals[t + 128];
        zl[t] = mu + eps[b * 128 + t] * expf(0.5f * lv);
        out_mu[b * 128 + t] = mu;
        out_lv[b * 128 + t] = lv;
    }
    __syncthreads();
    for (int c = t; c < 512; c += 256) {
        float a2 = z2h_b[c];
        const float* wz = z2h_w + (size_t)c * 128;
        for (int k = 0; k < 128; ++k) a2 += zl[k] * wz[k];
        hidden[(size_t)b * 512 + c] = f2bf(a2);
    }
}

// ---------------- standalone pred (final level d=6 only) ----------------
__global__ __launch_bounds__(256) void pred_mfma(
    const u16* __restrict__ hidden, const u16* __restrict__ Wo,
    const float* __restrict__ h2o_b, float* __restrict__ preds_out,
    int dlog, int node_base)
{
    const int lane = threadIdx.x & 63;
    const int wid  = threadIdx.x >> 6;
    const int lr = lane & 15, lk = lane >> 4;
    const int m0 = blockIdx.x * 64 + wid * 16;

    f32x4 acc0 = (f32x4){0.f, 0.f, 0.f, 0.f};
    f32x4 acc1 = (f32x4){0.f, 0.f, 0.f, 0.f};
    const u16* Arow = hidden + (size_t)(m0 + lr) * 512 + lk * 8;
    const u16* B0 = Wo + (size_t)lr * 512 + lk * 8;
    const u16* B1 = Wo + (size_t)(16 + lr) * 512 + lk * 8;
#pragma unroll
    for (int k0 = 0; k0 < 512; k0 += 32) {
        short8 a  = *reinterpret_cast<const short8*>(Arow + k0);
        short8 b0 = *reinterpret_cast<const short8*>(B0 + k0);
        short8 b1 = *reinterpret_cast<const short8*>(B1 + k0);
        acc0 = __builtin_amdgcn_mfma_f32_16x16x32_bf16(b0, a, acc0, 0, 0, 0);
        acc1 = __builtin_amdgcn_mfma_f32_16x16x32_bf16(b1, a, acc1, 0, 0, 0);
    }
    float4 bb0 = *reinterpret_cast<const float4*>(h2o_b + lk * 4);
    float4 bb1 = *reinterpret_cast<const float4*>(h2o_b + 16 + lk * 4);
    float p0[4], p1[4];
    p0[0] = acc0[0] + bb0.x; p0[1] = acc0[1] + bb0.y; p0[2] = acc0[2] + bb0.z; p0[3] = acc0[3] + bb0.w;
    p1[0] = acc1[0] + bb1.x; p1[1] = acc1[1] + bb1.y; p1[2] = acc1[2] + bb1.z; p1[3] = acc1[3] + bb1.w;
    int m = m0 + lr;
    int b_ = m >> dlog, j_ = m & ((1 << dlog) - 1);
    size_t o = (size_t)(b_ * 127 + node_base + j_) * 32;
    *reinterpret_cast<float4*>(preds_out + o + lk * 4)      = make_float4(p0[0], p0[1], p0[2], p0[3]);
    *reinterpret_cast<float4*>(preds_out + o + 16 + lk * 4) = make_float4(p1[0], p1[1], p1[2], p1[3]);
}

// ---------------- decoder: fused pred+softmax+GRU (swapped, 2-buffer drain-0) ----------------
template<int RF>
__global__ __launch_bounds__(256, 2) void dec_tile(
    const u16* __restrict__ Hin, const u16* __restrict__ Wh,
    const u16* __restrict__ Wi, const u16* __restrict__ Wo,
    const float* __restrict__ dbh, const float* __restrict__ dbi,
    const float* __restrict__ h2o_b, u16* __restrict__ Hout,
    float* __restrict__ preds_out, int dlog, int node_base)
{
    constexpr int BM = RF * 32;
    constexpr int NCA = BM / 64;
    constexpr int NS = 16;                 // K stages (512/32)
    __shared__ alignas(16) u16 Als[2][BM * 32];
    __shared__ alignas(16) u16 Bls[2][192 * 32];
    const int tid  = threadIdx.x;
    const int lane = tid & 63;
    const int wid  = tid >> 6;
    const int wr = wid >> 1, wc = wid & 1;
    const int lr = lane & 15, lk = lane >> 4;
    const int m0 = blockIdx.x * BM;
    const int c0 = blockIdx.y * 64;      // within 1024
    const int mask = (1 << dlog) - 1;

    size_t a_goff[NCA]; int a_loff[NCA];
#pragma unroll
    for (int j = 0; j < NCA; ++j) {
        int a = wid * NCA + j;
        int r_ = a * 16 + (lane >> 2);
        int kps = (lane & 3) ^ ((r_ >> 1) & 3);
        a_goff[j] = (size_t)(m0 + r_) * 512 + kps * 8;
        a_loff[j] = a * 512 + lane * 8;
    }
    size_t b_goff[3]; int b_loff[3];
#pragma unroll
    for (int j = 0; j < 3; ++j) {
        int b = wid * 3 + j;
        int rr = b * 16 + (lane >> 2);
        int kps = (lane & 3) ^ ((rr >> 1) & 3);
        int grow = (rr >> 6) * 1024 + c0 + (rr & 63);
        b_goff[j] = (size_t)grow * 512 + kps * 8;
        b_loff[j] = b * 512 + lane * 8;
    }
    int a_roff[RF];
#pragma unroll
    for (int i = 0; i < RF; ++i) {
        int row = wr * (RF * 16) + i * 16 + lr;
        a_roff[i] = row * 32 + (lk ^ ((row >> 1) & 3)) * 8;
    }
    int b_roff[3][2];
#pragma unroll
    for (int s = 0; s < 3; ++s)
#pragma unroll
        for (int cf = 0; cf < 2; ++cf) {
            int row = s * 64 + wc * 32 + cf * 16 + lr;
            b_roff[s][cf] = row * 32 + (lk ^ ((row >> 1) & 3)) * 8;
        }

    f32x4 acc[4][2][RF];
#pragma unroll
    for (int s = 0; s < 4; ++s)
#pragma unroll
        for (int cf = 0; cf < 2; ++cf)
#pragma unroll
            for (int i = 0; i < RF; ++i) acc[s][cf][i] = (f32x4){0.f, 0.f, 0.f, 0.f};
    f32x4 accp[2][RF];
#pragma unroll
    for (int cf = 0; cf < 2; ++cf)
#pragma unroll
        for (int i = 0; i < RF; ++i) accp[cf][i] = (f32x4){0.f, 0.f, 0.f, 0.f};

    auto issue = [&](int stg) {
        const int buf = stg & 1;
        const int nk = stg * 32;
#pragma unroll
        for (int j = 0; j < NCA; ++j) gload16(Hin + a_goff[j] + nk, &Als[buf][a_loff[j]]);
#pragma unroll
        for (int j = 0; j < 3; ++j) gload16(Wh + b_goff[j] + nk, &Bls[buf][b_loff[j]]);
    };
    auto compute = [&](int buf, int t) {
        short8 a[RF];
#pragma unroll
        for (int i = 0; i < RF; ++i)
            a[i] = *reinterpret_cast<const short8*>(&Als[buf][a_roff[i]]);
#pragma unroll
        for (int s = 0; s < 3; ++s)
#pragma unroll
            for (int cf = 0; cf < 2; ++cf) {
                short8 b = *reinterpret_cast<const short8*>(&Bls[buf][b_roff[s][cf]]);
#pragma unroll
                for (int i = 0; i < RF; ++i)
                    acc[s][cf][i] = __builtin_amdgcn_mfma_f32_16x16x32_bf16(b, a[i], acc[s][cf][i], 0, 0, 0);
            }
        // fused pred: Wo (32x512) fragments from global (L1-resident)
#pragma unroll
        for (int cf = 0; cf < 2; ++cf) {
            short8 wo = *reinterpret_cast<const short8*>(
                Wo + (size_t)(cf * 16 + lr) * 512 + t * 32 + lk * 8);
#pragma unroll
            for (int i = 0; i < RF; ++i)
                accp[cf][i] = __builtin_amdgcn_mfma_f32_16x16x32_bf16(wo, a[i], accp[cf][i], 0, 0, 0);
        }
    };

    issue(0);
    WAITV(0);
    __builtin_amdgcn_s_barrier();
    for (int t = 0; t < NS - 1; ++t) {
        issue(t + 1);
        compute(t & 1, t);
        WAITV(0);
        __builtin_amdgcn_s_barrier();
    }
    compute((NS - 1) & 1, NS - 1);

    // ---- softmax + write preds (y==0, wc==0) + stage a into LDS (wc==0) ----
    u16* aLds = &Als[0][0];     // BM x 32 bf16, buffers now free for reuse
    {
        float4 bb0 = *reinterpret_cast<const float4*>(h2o_b + lk * 4);
        float4 bb1 = *reinterpret_cast<const float4*>(h2o_b + 16 + lk * 4);
#pragma unroll
        for (int i = 0; i < RF; ++i) {
            float p0[4], p1[4];
            p0[0] = accp[0][i][0] + bb0.x; p0[1] = accp[0][i][1] + bb0.y;
            p0[2] = accp[0][i][2] + bb0.z; p0[3] = accp[0][i][3] + bb0.w;
            p1[0] = accp[1][i][0] + bb1.x; p1[1] = accp[1][i][1] + bb1.y;
            p1[2] = accp[1][i][2] + bb1.z; p1[3] = accp[1][i][3] + bb1.w;
            float mx = fmaxf(fmaxf(fmaxf(p0[0], p0[1]), fmaxf(p0[2], p0[3])),
                             fmaxf(fmaxf(p1[0], p1[1]), fmaxf(p1[2], p1[3])));
            mx = fmaxf(mx, __shfl_xor(mx, 16));
            mx = fmaxf(mx, __shfl_xor(mx, 32));
            float e0[4], e1[4], s = 0.0f;
#pragma unroll
            for (int r = 0; r < 4; ++r) {
                e0[r] = __expf(p0[r] - mx); e1[r] = __expf(p1[r] - mx);
                s += e0[r] + e1[r];
            }
            s += __shfl_xor(s, 16);
            s += __shfl_xor(s, 32);
            int mloc = wr * (RF * 16) + i * 16 + lr;
            int m = m0 + mloc;
            if (blockIdx.y == 0 && wc == 0) {
                int b_ = m >> dlog, j_ = m & mask;
                size_t o = (size_t)(b_ * 127 + node_base + j_) * 32;
                *reinterpret_cast<float4*>(preds_out + o + lk * 4)      = make_float4(p0[0], p0[1], p0[2], p0[3]);
                *reinterpret_cast<float4*>(preds_out + o + 16 + lk * 4) = make_float4(p1[0], p1[1], p1[2], p1[3]);
            }
            if (wc == 0) {
                float inv = __builtin_amdgcn_rcpf(s);
                ushort4 a0, a1;
                u16* av0 = reinterpret_cast<u16*>(&a0);
                u16* av1 = reinterpret_cast<u16*>(&a1);
#pragma unroll
                for (int r = 0; r < 4; ++r) { av0[r] = f2bf(e0[r] * inv); av1[r] = f2bf(e1[r] * inv); }
                *reinterpret_cast<ushort4*>(aLds + mloc * 32 + lk * 4)      = a0;
                *reinterpret_cast<ushort4*>(aLds + mloc * 32 + 16 + lk * 4) = a1;
            }
        }
    }
    __builtin_amdgcn_s_barrier();

    // rank-32 input-gate contribution (a from LDS)
#pragma unroll
    for (int i = 0; i < RF; ++i) {
        int mloc = wr * (RF * 16) + i * 16 + lr;
        short8 aw = *reinterpret_cast<const short8*>(aLds + mloc * 32 + lk * 8);
#pragma unroll
        for (int s = 0; s < 3; ++s) {
            const int d = (s == 2) ? 3 : s;
#pragma unroll
            for (int cf = 0; cf < 2; ++cf) {
                short8 b = *reinterpret_cast<const short8*>(
                    Wi + (size_t)(s * 1024 + c0 + wc * 32 + cf * 16 + lr) * 32 + lk * 8);
                acc[d][cf][i] = __builtin_amdgcn_mfma_f32_16x16x32_bf16(b, aw, acc[d][cf][i], 0, 0, 0);
            }
        }
    }

    // ---- epilogue ----
    float4 br4[2], bz4[2], bin4[2], bhn4[2];
    int cb[2];
#pragma unroll
    for (int cf = 0; cf < 2; ++cf) {
        cb[cf] = c0 + wc * 32 + cf * 16 + lk * 4;
        float4 h0 = *reinterpret_cast<const float4*>(dbh + cb[cf]);
        float4 i0 = *reinterpret_cast<const float4*>(dbi + cb[cf]);
        float4 h1 = *reinterpret_cast<const float4*>(dbh + 1024 + cb[cf]);
        float4 i1 = *reinterpret_cast<const float4*>(dbi + 1024 + cb[cf]);
        br4[cf] = make_float4(h0.x + i0.x, h0.y + i0.y, h0.z + i0.z, h0.w + i0.w);
        bz4[cf] = make_float4(h1.x + i1.x, h1.y + i1.y, h1.z + i1.z, h1.w + i1.w);
        bin4[cf] = *reinterpret_cast<const float4*>(dbi + 2048 + cb[cf]);
        bhn4[cf] = *reinterpret_cast<const float4*>(dbh + 2048 + cb[cf]);
    }
#pragma unroll
    for (int i = 0; i < RF; ++i) {
        int m = m0 + wr * (RF * 16) + i * 16 + lr;
#pragma unroll
        for (int cf = 0; cf < 2; ++cf) {
            ushort4 hid4 = *reinterpret_cast<const ushort4*>(Hin + (size_t)m * 512 + (cb[cf] & 511));
            const float b_r[4] = {br4[cf].x, br4[cf].y, br4[cf].z, br4[cf].w};
            const float b_z[4] = {bz4[cf].x, bz4[cf].y, bz4[cf].z, bz4[cf].w};
            const float b_in[4] = {bin4[cf].x, bin4[cf].y, bin4[cf].z, bin4[cf].w};
            const float b_hn[4] = {bhn4[cf].x, bhn4[cf].y, bhn4[cf].z, bhn4[cf].w};
            const u16 hv[4] = {hid4.x, hid4.y, hid4.z, hid4.w};
            ushort4 outv;
            u16* ov = reinterpret_cast<u16*>(&outv);
#pragma unroll
            for (int r = 0; r < 4; ++r) {
                float rr_ = fsig(acc[0][cf][i][r] + b_r[r]);
                float zz  = fsig(acc[1][cf][i][r] + b_z[r]);
                float nn  = ftanh(acc[3][cf][i][r] + b_in[r] + rr_ * (acc[2][cf][i][r] + b_hn[r]));
                ov[r] = f2bf((1.0f - zz) * nn + zz * bf2f(hv[r]));
            }
            *reinterpret_cast<ushort4*>(Hout + (size_t)m * 1024 + cb[cf]) = outv;
        }
    }
}

extern "C" void kernel_launch(void* const* d_in, const int* in_sizes, int n_in,
                              void* d_out, int out_size, void* d_ws, size_t ws_size,
                              hipStream_t stream) {
    const int*   symbols = (const int*)  d_in[0];
    const float* eps     = (const float*)d_in[1];
    const float* ewi     = (const float*)d_in[2];
    const float* ebi     = (const float*)d_in[3];
    const float* ewh     = (const float*)d_in[4];
    const float* ebh     = (const float*)d_in[5];
    const float* h2mu_w  = (const float*)d_in[6];
    const float* h2mu_b  = (const float*)d_in[7];
    const float* h2lv_w  = (const float*)d_in[8];
    const float* h2lv_b  = (const float*)d_in[9];
    const float* z2h_w   = (const float*)d_in[10];
    const float* z2h_b   = (const float*)d_in[11];
    const float* h2o_w   = (const float*)d_in[12];
    const float* h2o_b   = (const float*)d_in[13];
    const float* dwi     = (const float*)d_in[14];
    const float* dbi     = (const float*)d_in[15];
    const float* dwh     = (const float*)d_in[16];
    const float* dbh     = (const float*)d_in[17];

    float* out    = (float*)d_out;
    float* out_mu = out;
    float* out_lv = out + 256 * 128;
    float* out_pr = out + 2 * 256 * 128;

    // ---- workspace layout (~34.6 MB) ----
    u16* bufL  = (u16*)d_ws;                            // 16384*512
    u16* bufS  = bufL  + (size_t)16384 * 512;           //  8192*512
    u16* ewh_b = bufS  + (size_t)8192 * 512;            // 1536*1024
    u16* dwh_b = ewh_b + (size_t)1536 * 1024;           // 3072*512
    u16* dwi_b = dwh_b + (size_t)3072 * 512;            // 3072*32
    u16* ewi_b = dwi_b + (size_t)3072 * 32;             // 1536*32
    u16* wo_b  = ewi_b + (size_t)1536 * 32;             // 32*512
    u16* ltab  = wo_b  + (size_t)32 * 512;              // 32*512
    u16* oneh  = ltab  + (size_t)32 * 512;              // 32512*32

    // ---- single merged prep launch ----
    prep<<<(4366336 + 255) / 256, 256, 0, stream>>>(
        ewh, dwh, dwi, ewi, h2o_w, symbols, ebi, ebh,
        ewh_b, dwh_b, dwi_b, ewi_b, wo_b, oneh, ltab);

    // ---- encoder ---- d=5 fused with leaf (reads tab directly), writes bufS
    enc_tile<4, true><<<dim3(64, 8), 256, 0, stream>>>(
        nullptr, ewh_b, oneh, ewi_b, ltab, symbols, ebi, ebh, bufS, 5, 31);
    const u16* src = bufS;
    u16*       dst = bufL;
    for (int d = 4; d >= 0; --d) {
        int M = 256 << d;
        if (M >= 4096)
            enc_tile<4, false><<<dim3(M / 128, 8), 256, 0, stream>>>(
                src, ewh_b, oneh, ewi_b, ltab, symbols, ebi, ebh, dst, d, (1 << d) - 1);
        else
            enc_tile<2, false><<<dim3(M / 64, 8), 256, 0, stream>>>(
                src, ewh_b, oneh, ewi_b, ltab, symbols, ebi, ebh, dst, d, (1 << d) - 1);
        const u16* t = src; src = dst; dst = (u16*)t;
    }
    // root in bufL
    midf<<<256, 256, 0, stream>>>(src, h2mu_w, h2mu_b, h2lv_w, h2lv_b, eps,
                                  z2h_w, z2h_b, out_mu, out_lv, bufL);

    // ---- decoder (pred fused into dec_tile) ----
    const u16* hsrc = bufL;
    u16*       hdst = bufS;
    for (int d = 0; d < 6; ++d) {
        int M = 256 << d;
        if (M >= 4096)
            dec_tile<4><<<dim3(M / 128, 16), 256, 0, stream>>>(
                hsrc, dwh_b, dwi_b, wo_b, dbh, dbi, h2o_b, hdst, out_pr, d, (1 << d) - 1);
        else
            dec_tile<2><<<dim3(M / 64, 16), 256, 0, stream>>>(
                hsrc, dwh_b, dwi_b, wo_b, dbh, dbi, h2o_b, hdst, out_pr, d, (1 << d) - 1);
        const u16* t = hsrc; hsrc = hdst; hdst = (u16*)t;
    }
    pred_mfma<<<16384 / 64, 256, 0, stream>>>(hsrc, wo_b, h2o_b, out_pr, 6, 63);
}

// Round 18
// 336.935 us; speedup vs baseline: 1.2865x; 1.0322x over previous
//
#include <hip/hip_runtime.h>
#include <hip/hip_bf16.h>

typedef unsigned short u16;
typedef unsigned int u32;
typedef __attribute__((ext_vector_type(8))) short short8;   // 8 bf16 = 4 VGPR
typedef __attribute__((ext_vector_type(4))) float f32x4;

#define WAITV(N) asm volatile("s_waitcnt vmcnt(" #N ")" ::: "memory")

__device__ __forceinline__ float sigmoidf_(float x) { return 1.0f / (1.0f + expf(-x)); }
__device__ __forceinline__ float fsig(float x) {
    return __builtin_amdgcn_rcpf(1.0f + __expf(-x));
}
__device__ __forceinline__ float ftanh(float x) {
    x = fminf(fmaxf(x, -15.0f), 15.0f);
    float t = __expf(2.0f * x);
    return (t - 1.0f) * __builtin_amdgcn_rcpf(t + 1.0f);
}

__device__ __forceinline__ float bf2f(u16 u) {
    union { u32 i; float f; } v; v.i = ((u32)u) << 16; return v.f;
}
__device__ __forceinline__ u16 f2bf(float f) {
    union { float f; u32 i; } v; v.f = f;
    u32 lsb = (v.i >> 16) & 1u;
    v.i += 0x7fffu + lsb;            // RNE
    return (u16)(v.i >> 16);
}

__device__ __forceinline__ void gload16(const u16* g, u16* l) {
    __builtin_amdgcn_global_load_lds(
        (const __attribute__((address_space(1))) u32*)g,
        (__attribute__((address_space(3))) u32*)l, 16, 0, 0);
}

__device__ __forceinline__ ushort4 cvt4(const float* src) {
    float4 v = *reinterpret_cast<const float4*>(src);
    ushort4 o;
    o.x = f2bf(v.x); o.y = f2bf(v.y); o.z = f2bf(v.z); o.w = f2bf(v.w);
    return o;
}

// ---------------- merged prep (vectorized x4) ----------------
// segments (elems): ewh 1572864 | dwh 1572864 | dwi 98304 | ewi 49152 | h2o_w 16384 |
//                   oneh 1040384 | ltab 16384  -> total 4366336, /4 = 1091584 threads
__global__ __launch_bounds__(256) void prep(
    const float* __restrict__ ewh, const float* __restrict__ dwh,
    const float* __restrict__ dwi, const float* __restrict__ ewi,
    const float* __restrict__ h2o_w, const int* __restrict__ symbols,
    const float* __restrict__ ebi, const float* __restrict__ ebh,
    u16* __restrict__ ewh_b, u16* __restrict__ dwh_b, u16* __restrict__ dwi_b,
    u16* __restrict__ ewi_b, u16* __restrict__ wo_b, u16* __restrict__ oneh,
    u16* __restrict__ ltab)
{
    int idx = (blockIdx.x * 256 + threadIdx.x) * 4;
    if (idx < 1572864) { *reinterpret_cast<ushort4*>(ewh_b + idx) = cvt4(ewh + idx); return; }
    idx -= 1572864;
    if (idx < 1572864) { *reinterpret_cast<ushort4*>(dwh_b + idx) = cvt4(dwh + idx); return; }
    idx -= 1572864;
    if (idx < 98304) { *reinterpret_cast<ushort4*>(dwi_b + idx) = cvt4(dwi + idx); return; }
    idx -= 98304;
    if (idx < 49152) { *reinterpret_cast<ushort4*>(ewi_b + idx) = cvt4(ewi + idx); return; }
    idx -= 49152;
    if (idx < 16384) { *reinterpret_cast<ushort4*>(wo_b + idx) = cvt4(h2o_w + idx); return; }
    idx -= 16384;
    if (idx < 1040384) {
        int row = idx >> 5, col0 = idx & 31;
        int sym = symbols[row];
        ushort4 o;
        o.x = (col0 + 0 == sym) ? (u16)0x3F80 : (u16)0;
        o.y = (col0 + 1 == sym) ? (u16)0x3F80 : (u16)0;
        o.z = (col0 + 2 == sym) ? (u16)0x3F80 : (u16)0;
        o.w = (col0 + 3 == sym) ? (u16)0x3F80 : (u16)0;
        *reinterpret_cast<ushort4*>(oneh + idx) = o;
        return;
    }
    idx -= 1040384;
    if (idx < 16384) {
        int sym = idx >> 9, c0 = idx & 511;
        ushort4 o;
        u16* ov = reinterpret_cast<u16*>(&o);
#pragma unroll
        for (int r = 0; r < 4; ++r) {
            int c = c0 + r;
            float rr = sigmoidf_(ewi[c * 32 + sym]          + ebi[c]        + ebh[c]);
            float zz = sigmoidf_(ewi[(512 + c) * 32 + sym]  + ebi[512 + c]  + ebh[512 + c]);
            float nn = tanhf(    ewi[(1024 + c) * 32 + sym] + ebi[1024 + c] + rr * ebh[1024 + c]);
            ov[r] = f2bf((1.0f - zz) * nn);
        }
        *reinterpret_cast<ushort4*>(ltab + idx) = o;
    }
}

// ---------------- Encoder: 2-buffer drain-0 MFMA GEMM + GRU (unchanged, verified) ----------------
template<int RF, bool LEAF>
__global__ __launch_bounds__(256, 2) void enc_tile(
    const u16* __restrict__ A, const u16* __restrict__ W,
    const u16* __restrict__ oneh, const u16* __restrict__ Wi,
    const u16* __restrict__ tab, const int* __restrict__ symbols,
    const float* __restrict__ ebi, const float* __restrict__ ebh,
    u16* __restrict__ hout, int dlog, int node_base)
{
    constexpr int BM = RF * 32;
    constexpr int NCA = BM / 64;
    constexpr int NS = 32;
    __shared__ alignas(16) u16 Als[2][BM * 32];
    __shared__ alignas(16) u16 Bls[2][192 * 32];
    const int tid  = threadIdx.x;
    const int lane = tid & 63;
    const int wid  = tid >> 6;
    const int wr = wid >> 1, wc = wid & 1;
    const int lr = lane & 15, lk = lane >> 4;
    const int m0 = blockIdx.x * BM;
    const int c0 = blockIdx.y * 64;
    const int mask = (1 << dlog) - 1;

    size_t a_goff[NCA]; int a_loff[NCA];
    int symL[NCA], symR[NCA];
#pragma unroll
    for (int j = 0; j < NCA; ++j) {
        int a = wid * NCA + j;
        int r_ = a * 16 + (lane >> 2);
        int kps = (lane & 3) ^ ((r_ >> 1) & 3);
        a_loff[j] = a * 512 + lane * 8;
        if constexpr (LEAF) {
            int rg = m0 + r_;
            int b_ = rg >> dlog, jj = rg & mask;
            int cbase = b_ * 127 + 2 * (node_base + jj) + 1;
            symL[j] = symbols[cbase];
            symR[j] = symbols[cbase + 1];
            a_goff[j] = kps * 8;
        } else {
            a_goff[j] = (size_t)(m0 + r_) * 1024 + kps * 8;
            symL[j] = symR[j] = 0;
        }
    }
    size_t b_goff[3]; int b_loff[3];
#pragma unroll
    for (int j = 0; j < 3; ++j) {
        int b = wid * 3 + j;
        int rr = b * 16 + (lane >> 2);
        int kps = (lane & 3) ^ ((rr >> 1) & 3);
        int grow = (rr >> 6) * 512 + c0 + (rr & 63);
        b_goff[j] = (size_t)grow * 1024 + kps * 8;
        b_loff[j] = b * 512 + lane * 8;
    }
    int a_roff[RF];
#pragma unroll
    for (int i = 0; i < RF; ++i) {
        int row = wr * (RF * 16) + i * 16 + lr;
        a_roff[i] = row * 32 + (lk ^ ((row >> 1) & 3)) * 8;
    }
    int b_roff[3][2];
#pragma unroll
    for (int s = 0; s < 3; ++s)
#pragma unroll
        for (int cf = 0; cf < 2; ++cf) {
            int row = s * 64 + wc * 32 + cf * 16 + lr;
            b_roff[s][cf] = row * 32 + (lk ^ ((row >> 1) & 3)) * 8;
        }

    f32x4 acc[4][2][RF];
#pragma unroll
    for (int s = 0; s < 4; ++s)
#pragma unroll
        for (int cf = 0; cf < 2; ++cf)
#pragma unroll
            for (int i = 0; i < RF; ++i) acc[s][cf][i] = (f32x4){0.f, 0.f, 0.f, 0.f};

    auto issue = [&](int stg) {
        const int buf = stg & 1;
        const int nk = stg * 32;
#pragma unroll
        for (int j = 0; j < NCA; ++j) {
            if constexpr (LEAF) {
                const u16* src = (nk < 512)
                    ? tab + (size_t)symL[j] * 512 + nk + a_goff[j]
                    : tab + (size_t)symR[j] * 512 + (nk - 512) + a_goff[j];
                gload16(src, &Als[buf][a_loff[j]]);
            } else {
                gload16(A + a_goff[j] + nk, &Als[buf][a_loff[j]]);
            }
        }
#pragma unroll
        for (int j = 0; j < 3; ++j) gload16(W + b_goff[j] + nk, &Bls[buf][b_loff[j]]);
    };
    auto compute = [&](int buf) {
        short8 a[RF];
#pragma unroll
        for (int i = 0; i < RF; ++i)
            a[i] = *reinterpret_cast<const short8*>(&Als[buf][a_roff[i]]);
#pragma unroll
        for (int s = 0; s < 3; ++s)
#pragma unroll
            for (int cf = 0; cf < 2; ++cf) {
                short8 b = *reinterpret_cast<const short8*>(&Bls[buf][b_roff[s][cf]]);
#pragma unroll
                for (int i = 0; i < RF; ++i)
                    acc[s][cf][i] = __builtin_amdgcn_mfma_f32_16x16x32_bf16(b, a[i], acc[s][cf][i], 0, 0, 0);
            }
    };

    issue(0);
    WAITV(0);
    __builtin_amdgcn_s_barrier();
    for (int t = 0; t < NS - 1; ++t) {
        issue(t + 1);
        compute(t & 1);
        WAITV(0);
        __builtin_amdgcn_s_barrier();
    }
    compute((NS - 1) & 1);

    {
        short8 oh[RF];
#pragma unroll
        for (int i = 0; i < RF; ++i) {
            int m = m0 + wr * (RF * 16) + i * 16 + lr;
            int b_ = m >> dlog, j_ = m & mask;
            oh[i] = *reinterpret_cast<const short8*>(
                oneh + (size_t)(b_ * 127 + node_base + j_) * 32 + lk * 8);
        }
#pragma unroll
        for (int s = 0; s < 3; ++s) {
            const int d = (s == 2) ? 3 : s;
#pragma unroll
            for (int cf = 0; cf < 2; ++cf) {
                short8 wb = *reinterpret_cast<const short8*>(
                    Wi + (size_t)(s * 512 + c0 + wc * 32 + cf * 16 + lr) * 32 + lk * 8);
#pragma unroll
                for (int i = 0; i < RF; ++i)
                    acc[d][cf][i] = __builtin_amdgcn_mfma_f32_16x16x32_bf16(wb, oh[i], acc[d][cf][i], 0, 0, 0);
            }
        }
    }

    float4 ebr4[2], ebz4[2], ebin4[2], ebhn4[2];
    int cb[2];
#pragma unroll
    for (int cf = 0; cf < 2; ++cf) {
        cb[cf] = c0 + wc * 32 + cf * 16 + lk * 4;
        float4 bi0 = *reinterpret_cast<const float4*>(ebi + cb[cf]);
        float4 bh0 = *reinterpret_cast<const float4*>(ebh + cb[cf]);
        float4 bi1 = *reinterpret_cast<const float4*>(ebi + 512 + cb[cf]);
        float4 bh1 = *reinterpret_cast<const float4*>(ebh + 512 + cb[cf]);
        ebr4[cf] = make_float4(bi0.x + bh0.x, bi0.y + bh0.y, bi0.z + bh0.z, bi0.w + bh0.w);
        ebz4[cf] = make_float4(bi1.x + bh1.x, bi1.y + bh1.y, bi1.z + bh1.z, bi1.w + bh1.w);
        ebin4[cf] = *reinterpret_cast<const float4*>(ebi + 1024 + cb[cf]);
        ebhn4[cf] = *reinterpret_cast<const float4*>(ebh + 1024 + cb[cf]);
    }
#pragma unroll
    for (int i = 0; i < RF; ++i) {
        int m = m0 + wr * (RF * 16) + i * 16 + lr;
        int symLm = 0, symRm = 0;
        if constexpr (LEAF) {
            int b_ = m >> dlog, jj = m & mask;
            int cbase_ = b_ * 127 + 2 * (node_base + jj) + 1;
            symLm = symbols[cbase_];
            symRm = symbols[cbase_ + 1];
        }
#pragma unroll
        for (int cf = 0; cf < 2; ++cf) {
            ushort4 hl4, hr4;
            if constexpr (LEAF) {
                hl4 = *reinterpret_cast<const ushort4*>(tab + (size_t)symLm * 512 + cb[cf]);
                hr4 = *reinterpret_cast<const ushort4*>(tab + (size_t)symRm * 512 + cb[cf]);
            } else {
                hl4 = *reinterpret_cast<const ushort4*>(A + (size_t)m * 1024 + cb[cf]);
                hr4 = *reinterpret_cast<const ushort4*>(A + (size_t)m * 1024 + 512 + cb[cf]);
            }
            const float eb_r[4] = {ebr4[cf].x, ebr4[cf].y, ebr4[cf].z, ebr4[cf].w};
            const float eb_z[4] = {ebz4[cf].x, ebz4[cf].y, ebz4[cf].z, ebz4[cf].w};
            const float eb_in[4] = {ebin4[cf].x, ebin4[cf].y, ebin4[cf].z, ebin4[cf].w};
            const float eb_hn[4] = {ebhn4[cf].x, ebhn4[cf].y, ebhn4[cf].z, ebhn4[cf].w};
            const u16 hlv[4] = {hl4.x, hl4.y, hl4.z, hl4.w};
            const u16 hrv[4] = {hr4.x, hr4.y, hr4.z, hr4.w};
            ushort4 outv;
            u16* ov = reinterpret_cast<u16*>(&outv);
#pragma unroll
            for (int r = 0; r < 4; ++r) {
                float rr_ = fsig(acc[0][cf][i][r] + eb_r[r]);
                float zz  = fsig(acc[1][cf][i][r] + eb_z[r]);
                float nn  = ftanh(acc[3][cf][i][r] + eb_in[r] + rr_ * (acc[2][cf][i][r] + eb_hn[r]));
                float hm = (bf2f(hlv[r]) + bf2f(hrv[r])) * 0.5f;
                ov[r] = f2bf((1.0f - zz) * nn + zz * hm);
            }
            *reinterpret_cast<ushort4*>(hout + (size_t)m * 512 + cb[cf]) = outv;
        }
    }
}

// ---------------- fused mid: mu/logvar/zlat + hidden0 ----------------
__global__ __launch_bounds__(256) void midf(
    const u16* __restrict__ root, const float* __restrict__ h2mu_w,
    const float* __restrict__ h2mu_b, const float* __restrict__ h2lv_w,
    const float* __restrict__ h2lv_b, const float* __restrict__ eps,
    const float* __restrict__ z2h_w, const float* __restrict__ z2h_b,
    float* __restrict__ out_mu, float* __restrict__ out_lv,
    u16* __restrict__ hidden)
{
    int b = blockIdx.x, t = threadIdx.x;
    __shared__ float rs[512];
    __shared__ float zl[128];
    rs[t]       = bf2f(root[(size_t)b * 512 + t]);
    rs[t + 256] = bf2f(root[(size_t)b * 512 + t + 256]);
    __syncthreads();
    const float* w = (t < 128) ? (h2mu_w + (size_t)t * 512) : (h2lv_w + (size_t)(t - 128) * 512);
    float acc = 0.0f;
    for (int k = 0; k < 512; ++k) acc += rs[k] * w[k];
    acc += (t < 128) ? h2mu_b[t] : h2lv_b[t - 128];
    __shared__ float vals[256];
    vals[t] = acc;
    __syncthreads();
    if (t < 128) {
        float mu = vals[t], lv = vals[t + 128];
        zl[t] = mu + eps[b * 128 + t] * expf(0.5f * lv);
        out_mu[b * 128 + t] = mu;
        out_lv[b * 128 + t] = lv;
    }
    __syncthreads();
    for (int c = t; c < 512; c += 256) {
        float a2 = z2h_b[c];
        const float* wz = z2h_w + (size_t)c * 128;
        for (int k = 0; k < 128; ++k) a2 += zl[k] * wz[k];
        hidden[(size_t)b * 512 + c] = f2bf(a2);
    }
}

// ---------------- final pred (d=6): K-split across 4 waves + LDS reduce ----------------
// grid = 16384/16 = 1024 blocks; block = 16 rows; wave w handles K slice [w*128,(w+1)*128).
__global__ __launch_bounds__(256) void pred_final(
    const u16* __restrict__ hidden, const u16* __restrict__ Wo,
    const float* __restrict__ h2o_b, float* __restrict__ preds_out)
{
    __shared__ float pbuf[4][32][17];
    const int tid = threadIdx.x;
    const int lane = tid & 63;
    const int w = tid >> 6;
    const int lr = lane & 15, lk = lane >> 4;
    const int m0 = blockIdx.x * 16;

    f32x4 acc0 = (f32x4){0.f, 0.f, 0.f, 0.f};
    f32x4 acc1 = (f32x4){0.f, 0.f, 0.f, 0.f};
    const u16* Arow = hidden + (size_t)(m0 + lr) * 512 + w * 128 + lk * 8;
    const u16* B0 = Wo + (size_t)lr * 512 + w * 128 + lk * 8;
    const u16* B1 = Wo + (size_t)(16 + lr) * 512 + w * 128 + lk * 8;
#pragma unroll
    for (int k0 = 0; k0 < 128; k0 += 32) {
        short8 a  = *reinterpret_cast<const short8*>(Arow + k0);
        short8 b0 = *reinterpret_cast<const short8*>(B0 + k0);
        short8 b1 = *reinterpret_cast<const short8*>(B1 + k0);
        acc0 = __builtin_amdgcn_mfma_f32_16x16x32_bf16(b0, a, acc0, 0, 0, 0);
        acc1 = __builtin_amdgcn_mfma_f32_16x16x32_bf16(b1, a, acc1, 0, 0, 0);
    }
#pragma unroll
    for (int r = 0; r < 4; ++r) {
        pbuf[w][lk * 4 + r][lr]      = acc0[r];
        pbuf[w][16 + lk * 4 + r][lr] = acc1[r];
    }
    __syncthreads();
#pragma unroll
    for (int it = 0; it < 2; ++it) {
        int o = tid + it * 256;             // 0..511 = 16 rows x 32 syms
        int mloc = o >> 5, sym = o & 31;
        float p = pbuf[0][sym][mloc] + pbuf[1][sym][mloc]
                + pbuf[2][sym][mloc] + pbuf[3][sym][mloc] + h2o_b[sym];
        int m = m0 + mloc;
        int b_ = m >> 6, j_ = m & 63;
        preds_out[(size_t)(b_ * 127 + 63 + j_) * 32 + sym] = p;
    }
}

// ---------------- decoder: fused pred+softmax+GRU (pred only in wc==0 waves) ----------------
template<int RF>
__global__ __launch_bounds__(256, 2) void dec_tile(
    const u16* __restrict__ Hin, const u16* __restrict__ Wh,
    const u16* __restrict__ Wi, const u16* __restrict__ Wo,
    const float* __restrict__ dbh, const float* __restrict__ dbi,
    const float* __restrict__ h2o_b, u16* __restrict__ Hout,
    float* __restrict__ preds_out, int dlog, int node_base)
{
    constexpr int BM = RF * 32;
    constexpr int NCA = BM / 64;
    constexpr int NS = 16;                 // K stages (512/32)
    __shared__ alignas(16) u16 Als[2][BM * 32];
    __shared__ alignas(16) u16 Bls[2][192 * 32];
    const int tid  = threadIdx.x;
    const int lane = tid & 63;
    const int wid  = tid >> 6;
    const int wr = wid >> 1, wc = wid & 1;
    const int lr = lane & 15, lk = lane >> 4;
    const int m0 = blockIdx.x * BM;
    const int c0 = blockIdx.y * 64;      // within 1024
    const int mask = (1 << dlog) - 1;

    size_t a_goff[NCA]; int a_loff[NCA];
#pragma unroll
    for (int j = 0; j < NCA; ++j) {
        int a = wid * NCA + j;
        int r_ = a * 16 + (lane >> 2);
        int kps = (lane & 3) ^ ((r_ >> 1) & 3);
        a_goff[j] = (size_t)(m0 + r_) * 512 + kps * 8;
        a_loff[j] = a * 512 + lane * 8;
    }
    size_t b_goff[3]; int b_loff[3];
#pragma unroll
    for (int j = 0; j < 3; ++j) {
        int b = wid * 3 + j;
        int rr = b * 16 + (lane >> 2);
        int kps = (lane & 3) ^ ((rr >> 1) & 3);
        int grow = (rr >> 6) * 1024 + c0 + (rr & 63);
        b_goff[j] = (size_t)grow * 512 + kps * 8;
        b_loff[j] = b * 512 + lane * 8;
    }
    int a_roff[RF];
#pragma unroll
    for (int i = 0; i < RF; ++i) {
        int row = wr * (RF * 16) + i * 16 + lr;
        a_roff[i] = row * 32 + (lk ^ ((row >> 1) & 3)) * 8;
    }
    int b_roff[3][2];
#pragma unroll
    for (int s = 0; s < 3; ++s)
#pragma unroll
        for (int cf = 0; cf < 2; ++cf) {
            int row = s * 64 + wc * 32 + cf * 16 + lr;
            b_roff[s][cf] = row * 32 + (lk ^ ((row >> 1) & 3)) * 8;
        }

    f32x4 acc[4][2][RF];
#pragma unroll
    for (int s = 0; s < 4; ++s)
#pragma unroll
        for (int cf = 0; cf < 2; ++cf)
#pragma unroll
            for (int i = 0; i < RF; ++i) acc[s][cf][i] = (f32x4){0.f, 0.f, 0.f, 0.f};
    f32x4 accp[2][RF];
#pragma unroll
    for (int cf = 0; cf < 2; ++cf)
#pragma unroll
        for (int i = 0; i < RF; ++i) accp[cf][i] = (f32x4){0.f, 0.f, 0.f, 0.f};

    auto issue = [&](int stg) {
        const int buf = stg & 1;
        const int nk = stg * 32;
#pragma unroll
        for (int j = 0; j < NCA; ++j) gload16(Hin + a_goff[j] + nk, &Als[buf][a_loff[j]]);
#pragma unroll
        for (int j = 0; j < 3; ++j) gload16(Wh + b_goff[j] + nk, &Bls[buf][b_loff[j]]);
    };
    auto compute = [&](int buf, int t) {
        short8 a[RF];
#pragma unroll
        for (int i = 0; i < RF; ++i)
            a[i] = *reinterpret_cast<const short8*>(&Als[buf][a_roff[i]]);
#pragma unroll
        for (int s = 0; s < 3; ++s)
#pragma unroll
            for (int cf = 0; cf < 2; ++cf) {
                short8 b = *reinterpret_cast<const short8*>(&Bls[buf][b_roff[s][cf]]);
#pragma unroll
                for (int i = 0; i < RF; ++i)
                    acc[s][cf][i] = __builtin_amdgcn_mfma_f32_16x16x32_bf16(b, a[i], acc[s][cf][i], 0, 0, 0);
            }
        // fused pred only in wc==0 waves (uniform branch); wc==1 never uses accp
        if (wc == 0) {
#pragma unroll
            for (int cf = 0; cf < 2; ++cf) {
                short8 wo = *reinterpret_cast<const short8*>(
                    Wo + (size_t)(cf * 16 + lr) * 512 + t * 32 + lk * 8);
#pragma unroll
                for (int i = 0; i < RF; ++i)
                    accp[cf][i] = __builtin_amdgcn_mfma_f32_16x16x32_bf16(wo, a[i], accp[cf][i], 0, 0, 0);
            }
        }
    };

    issue(0);
    WAITV(0);
    __builtin_amdgcn_s_barrier();
    for (int t = 0; t < NS - 1; ++t) {
        issue(t + 1);
        compute(t & 1, t);
        WAITV(0);
        __builtin_amdgcn_s_barrier();
    }
    compute((NS - 1) & 1, NS - 1);

    // ---- softmax + write preds (y==0) + stage a into LDS -- wc==0 waves only ----
    u16* aLds = &Als[0][0];     // BM x 32 bf16 (Als[0] free: last compute read Als[1])
    if (wc == 0) {
        float4 bb0 = *reinterpret_cast<const float4*>(h2o_b + lk * 4);
        float4 bb1 = *reinterpret_cast<const float4*>(h2o_b + 16 + lk * 4);
#pragma unroll
        for (int i = 0; i < RF; ++i) {
            float p0[4], p1[4];
            p0[0] = accp[0][i][0] + bb0.x; p0[1] = accp[0][i][1] + bb0.y;
            p0[2] = accp[0][i][2] + bb0.z; p0[3] = accp[0][i][3] + bb0.w;
            p1[0] = accp[1][i][0] + bb1.x; p1[1] = accp[1][i][1] + bb1.y;
            p1[2] = accp[1][i][2] + bb1.z; p1[3] = accp[1][i][3] + bb1.w;
            float mx = fmaxf(fmaxf(fmaxf(p0[0], p0[1]), fmaxf(p0[2], p0[3])),
                             fmaxf(fmaxf(p1[0], p1[1]), fmaxf(p1[2], p1[3])));
            mx = fmaxf(mx, __shfl_xor(mx, 16));
            mx = fmaxf(mx, __shfl_xor(mx, 32));
            float e0[4], e1[4], s = 0.0f;
#pragma unroll
            for (int r = 0; r < 4; ++r) {
                e0[r] = __expf(p0[r] - mx); e1[r] = __expf(p1[r] - mx);
                s += e0[r] + e1[r];
            }
            s += __shfl_xor(s, 16);
            s += __shfl_xor(s, 32);
            int mloc = wr * (RF * 16) + i * 16 + lr;
            int m = m0 + mloc;
            if (blockIdx.y == 0) {
                int b_ = m >> dlog, j_ = m & mask;
                size_t o = (size_t)(b_ * 127 + node_base + j_) * 32;
                *reinterpret_cast<float4*>(preds_out + o + lk * 4)      = make_float4(p0[0], p0[1], p0[2], p0[3]);
                *reinterpret_cast<float4*>(preds_out + o + 16 + lk * 4) = make_float4(p1[0], p1[1], p1[2], p1[3]);
            }
            float inv = __builtin_amdgcn_rcpf(s);
            ushort4 a0, a1;
            u16* av0 = reinterpret_cast<u16*>(&a0);
            u16* av1 = reinterpret_cast<u16*>(&a1);
#pragma unroll
            for (int r = 0; r < 4; ++r) { av0[r] = f2bf(e0[r] * inv); av1[r] = f2bf(e1[r] * inv); }
            *reinterpret_cast<ushort4*>(aLds + mloc * 32 + lk * 4)      = a0;
            *reinterpret_cast<ushort4*>(aLds + mloc * 32 + 16 + lk * 4) = a1;
        }
    }
    __builtin_amdgcn_s_barrier();

    // rank-32 input-gate contribution (a from LDS)
#pragma unroll
    for (int i = 0; i < RF; ++i) {
        int mloc = wr * (RF * 16) + i * 16 + lr;
        short8 aw = *reinterpret_cast<const short8*>(aLds + mloc * 32 + lk * 8);
#pragma unroll
        for (int s = 0; s < 3; ++s) {
            const int d = (s == 2) ? 3 : s;
#pragma unroll
            for (int cf = 0; cf < 2; ++cf) {
                short8 b = *reinterpret_cast<const short8*>(
                    Wi + (size_t)(s * 1024 + c0 + wc * 32 + cf * 16 + lr) * 32 + lk * 8);
                acc[d][cf][i] = __builtin_amdgcn_mfma_f32_16x16x32_bf16(b, aw, acc[d][cf][i], 0, 0, 0);
            }
        }
    }

    // ---- epilogue ----
    float4 br4[2], bz4[2], bin4[2], bhn4[2];
    int cb[2];
#pragma unroll
    for (int cf = 0; cf < 2; ++cf) {
        cb[cf] = c0 + wc * 32 + cf * 16 + lk * 4;
        float4 h0 = *reinterpret_cast<const float4*>(dbh + cb[cf]);
        float4 i0 = *reinterpret_cast<const float4*>(dbi + cb[cf]);
        float4 h1 = *reinterpret_cast<const float4*>(dbh + 1024 + cb[cf]);
        float4 i1 = *reinterpret_cast<const float4*>(dbi + 1024 + cb[cf]);
        br4[cf] = make_float4(h0.x + i0.x, h0.y + i0.y, h0.z + i0.z, h0.w + i0.w);
        bz4[cf] = make_float4(h1.x + i1.x, h1.y + i1.y, h1.z + i1.z, h1.w + i1.w);
        bin4[cf] = *reinterpret_cast<const float4*>(dbi + 2048 + cb[cf]);
        bhn4[cf] = *reinterpret_cast<const float4*>(dbh + 2048 + cb[cf]);
    }
#pragma unroll
    for (int i = 0; i < RF; ++i) {
        int m = m0 + wr * (RF * 16) + i * 16 + lr;
#pragma unroll
        for (int cf = 0; cf < 2; ++cf) {
            ushort4 hid4 = *reinterpret_cast<const ushort4*>(Hin + (size_t)m * 512 + (cb[cf] & 511));
            const float b_r[4] = {br4[cf].x, br4[cf].y, br4[cf].z, br4[cf].w};
            const float b_z[4] = {bz4[cf].x, bz4[cf].y, bz4[cf].z, bz4[cf].w};
            const float b_in[4] = {bin4[cf].x, bin4[cf].y, bin4[cf].z, bin4[cf].w};
            const float b_hn[4] = {bhn4[cf].x, bhn4[cf].y, bhn4[cf].z, bhn4[cf].w};
            const u16 hv[4] = {hid4.x, hid4.y, hid4.z, hid4.w};
            ushort4 outv;
            u16* ov = reinterpret_cast<u16*>(&outv);
#pragma unroll
            for (int r = 0; r < 4; ++r) {
                float rr_ = fsig(acc[0][cf][i][r] + b_r[r]);
                float zz  = fsig(acc[1][cf][i][r] + b_z[r]);
                float nn  = ftanh(acc[3][cf][i][r] + b_in[r] + rr_ * (acc[2][cf][i][r] + b_hn[r]));
                ov[r] = f2bf((1.0f - zz) * nn + zz * bf2f(hv[r]));
            }
            *reinterpret_cast<ushort4*>(Hout + (size_t)m * 1024 + cb[cf]) = outv;
        }
    }
}

extern "C" void kernel_launch(void* const* d_in, const int* in_sizes, int n_in,
                              void* d_out, int out_size, void* d_ws, size_t ws_size,
                              hipStream_t stream) {
    const int*   symbols = (const int*)  d_in[0];
    const float* eps     = (const float*)d_in[1];
    const float* ewi     = (const float*)d_in[2];
    const float* ebi     = (const float*)d_in[3];
    const float* ewh     = (const float*)d_in[4];
    const float* ebh     = (const float*)d_in[5];
    const float* h2mu_w  = (const float*)d_in[6];
    const float* h2mu_b  = (const float*)d_in[7];
    const float* h2lv_w  = (const float*)d_in[8];
    const float* h2lv_b  = (const float*)d_in[9];
    const float* z2h_w   = (const float*)d_in[10];
    const float* z2h_b   = (const float*)d_in[11];
    const float* h2o_w   = (const float*)d_in[12];
    const float* h2o_b   = (const float*)d_in[13];
    const float* dwi     = (const float*)d_in[14];
    const float* dbi     = (const float*)d_in[15];
    const float* dwh     = (const float*)d_in[16];
    const float* dbh     = (const float*)d_in[17];

    float* out    = (float*)d_out;
    float* out_mu = out;
    float* out_lv = out + 256 * 128;
    float* out_pr = out + 2 * 256 * 128;

    // ---- workspace layout (~34.6 MB) ----
    u16* bufL  = (u16*)d_ws;                            // 16384*512
    u16* bufS  = bufL  + (size_t)16384 * 512;           //  8192*512
    u16* ewh_b = bufS  + (size_t)8192 * 512;            // 1536*1024
    u16* dwh_b = ewh_b + (size_t)1536 * 1024;           // 3072*512
    u16* dwi_b = dwh_b + (size_t)3072 * 512;            // 3072*32
    u16* ewi_b = dwi_b + (size_t)3072 * 32;             // 1536*32
    u16* wo_b  = ewi_b + (size_t)1536 * 32;             // 32*512
    u16* ltab  = wo_b  + (size_t)32 * 512;              // 32*512
    u16* oneh  = ltab  + (size_t)32 * 512;              // 32512*32

    // ---- single merged prep launch (vec4) ----
    prep<<<(1091584 + 255) / 256, 256, 0, stream>>>(
        ewh, dwh, dwi, ewi, h2o_w, symbols, ebi, ebh,
        ewh_b, dwh_b, dwi_b, ewi_b, wo_b, oneh, ltab);

    // ---- encoder ---- d=5 fused with leaf (reads tab directly), writes bufS
    enc_tile<4, true><<<dim3(64, 8), 256, 0, stream>>>(
        nullptr, ewh_b, oneh, ewi_b, ltab, symbols, ebi, ebh, bufS, 5, 31);
    const u16* src = bufS;
    u16*       dst = bufL;
    for (int d = 4; d >= 0; --d) {
        int M = 256 << d;
        if (M >= 4096)
            enc_tile<4, false><<<dim3(M / 128, 8), 256, 0, stream>>>(
                src, ewh_b, oneh, ewi_b, ltab, symbols, ebi, ebh, dst, d, (1 << d) - 1);
        else
            enc_tile<2, false><<<dim3(M / 64, 8), 256, 0, stream>>>(
                src, ewh_b, oneh, ewi_b, ltab, symbols, ebi, ebh, dst, d, (1 << d) - 1);
        const u16* t = src; src = dst; dst = (u16*)t;
    }
    // root in bufL
    midf<<<256, 256, 0, stream>>>(src, h2mu_w, h2mu_b, h2lv_w, h2lv_b, eps,
                                  z2h_w, z2h_b, out_mu, out_lv, bufL);

    // ---- decoder (pred fused into dec_tile) ----
    const u16* hsrc = bufL;
    u16*       hdst = bufS;
    for (int d = 0; d < 6; ++d) {
        int M = 256 << d;
        if (M >= 4096)
            dec_tile<4><<<dim3(M / 128, 16), 256, 0, stream>>>(
                hsrc, dwh_b, dwi_b, wo_b, dbh, dbi, h2o_b, hdst, out_pr, d, (1 << d) - 1);
        else
            dec_tile<2><<<dim3(M / 64, 16), 256, 0, stream>>>(
                hsrc, dwh_b, dwi_b, wo_b, dbh, dbi, h2o_b, hdst, out_pr, d, (1 << d) - 1);
        const u16* t = hsrc; hsrc = hdst; hdst = (u16*)t;
    }
    pred_final<<<16384 / 16, 256, 0, stream>>>(hsrc, wo_b, h2o_b, out_pr);
}

// Round 19
// 336.044 us; speedup vs baseline: 1.2899x; 1.0027x over previous
//
#include <hip/hip_runtime.h>
#include <hip/hip_bf16.h>

typedef unsigned short u16;
typedef unsigned int u32;
typedef __attribute__((ext_vector_type(8))) short short8;   // 8 bf16 = 4 VGPR
typedef __attribute__((ext_vector_type(4))) float f32x4;

#define WAITV(N) asm volatile("s_waitcnt vmcnt(" #N ")" ::: "memory")

__device__ __forceinline__ float sigmoidf_(float x) { return 1.0f / (1.0f + expf(-x)); }
__device__ __forceinline__ float fsig(float x) {
    return __builtin_amdgcn_rcpf(1.0f + __expf(-x));
}
__device__ __forceinline__ float ftanh(float x) {
    x = fminf(fmaxf(x, -15.0f), 15.0f);
    float t = __expf(2.0f * x);
    return (t - 1.0f) * __builtin_amdgcn_rcpf(t + 1.0f);
}

__device__ __forceinline__ float bf2f(u16 u) {
    union { u32 i; float f; } v; v.i = ((u32)u) << 16; return v.f;
}
__device__ __forceinline__ u16 f2bf(float f) {
    union { float f; u32 i; } v; v.f = f;
    u32 lsb = (v.i >> 16) & 1u;
    v.i += 0x7fffu + lsb;            // RNE
    return (u16)(v.i >> 16);
}

__device__ __forceinline__ void gload16(const u16* g, u16* l) {
    __builtin_amdgcn_global_load_lds(
        (const __attribute__((address_space(1))) u32*)g,
        (__attribute__((address_space(3))) u32*)l, 16, 0, 0);
}

__device__ __forceinline__ ushort4 cvt4(const float* src) {
    float4 v = *reinterpret_cast<const float4*>(src);
    ushort4 o;
    o.x = f2bf(v.x); o.y = f2bf(v.y); o.z = f2bf(v.z); o.w = f2bf(v.w);
    return o;
}

// ---------------- merged prep (vectorized x4) ----------------
__global__ __launch_bounds__(256) void prep(
    const float* __restrict__ ewh, const float* __restrict__ dwh,
    const float* __restrict__ dwi, const float* __restrict__ ewi,
    const float* __restrict__ h2o_w, const int* __restrict__ symbols,
    const float* __restrict__ ebi, const float* __restrict__ ebh,
    u16* __restrict__ ewh_b, u16* __restrict__ dwh_b, u16* __restrict__ dwi_b,
    u16* __restrict__ ewi_b, u16* __restrict__ wo_b, u16* __restrict__ oneh,
    u16* __restrict__ ltab)
{
    int idx = (blockIdx.x * 256 + threadIdx.x) * 4;
    if (idx < 1572864) { *reinterpret_cast<ushort4*>(ewh_b + idx) = cvt4(ewh + idx); return; }
    idx -= 1572864;
    if (idx < 1572864) { *reinterpret_cast<ushort4*>(dwh_b + idx) = cvt4(dwh + idx); return; }
    idx -= 1572864;
    if (idx < 98304) { *reinterpret_cast<ushort4*>(dwi_b + idx) = cvt4(dwi + idx); return; }
    idx -= 98304;
    if (idx < 49152) { *reinterpret_cast<ushort4*>(ewi_b + idx) = cvt4(ewi + idx); return; }
    idx -= 49152;
    if (idx < 16384) { *reinterpret_cast<ushort4*>(wo_b + idx) = cvt4(h2o_w + idx); return; }
    idx -= 16384;
    if (idx < 1040384) {
        int row = idx >> 5, col0 = idx & 31;
        int sym = symbols[row];
        ushort4 o;
        o.x = (col0 + 0 == sym) ? (u16)0x3F80 : (u16)0;
        o.y = (col0 + 1 == sym) ? (u16)0x3F80 : (u16)0;
        o.z = (col0 + 2 == sym) ? (u16)0x3F80 : (u16)0;
        o.w = (col0 + 3 == sym) ? (u16)0x3F80 : (u16)0;
        *reinterpret_cast<ushort4*>(oneh + idx) = o;
        return;
    }
    idx -= 1040384;
    if (idx < 16384) {
        int sym = idx >> 9, c0 = idx & 511;
        ushort4 o;
        u16* ov = reinterpret_cast<u16*>(&o);
#pragma unroll
        for (int r = 0; r < 4; ++r) {
            int c = c0 + r;
            float rr = sigmoidf_(ewi[c * 32 + sym]          + ebi[c]        + ebh[c]);
            float zz = sigmoidf_(ewi[(512 + c) * 32 + sym]  + ebi[512 + c]  + ebh[512 + c]);
            float nn = tanhf(    ewi[(1024 + c) * 32 + sym] + ebi[1024 + c] + rr * ebh[1024 + c]);
            ov[r] = f2bf((1.0f - zz) * nn);
        }
        *reinterpret_cast<ushort4*>(ltab + idx) = o;
    }
}

// ---------------- Encoder: 2-buffer drain-0 MFMA GEMM + GRU (unchanged, verified) ----------------
template<int RF, bool LEAF>
__global__ __launch_bounds__(256, 2) void enc_tile(
    const u16* __restrict__ A, const u16* __restrict__ W,
    const u16* __restrict__ oneh, const u16* __restrict__ Wi,
    const u16* __restrict__ tab, const int* __restrict__ symbols,
    const float* __restrict__ ebi, const float* __restrict__ ebh,
    u16* __restrict__ hout, int dlog, int node_base)
{
    constexpr int BM = RF * 32;
    constexpr int NCA = BM / 64;
    constexpr int NS = 32;
    __shared__ alignas(16) u16 Als[2][BM * 32];
    __shared__ alignas(16) u16 Bls[2][192 * 32];
    const int tid  = threadIdx.x;
    const int lane = tid & 63;
    const int wid  = tid >> 6;
    const int wr = wid >> 1, wc = wid & 1;
    const int lr = lane & 15, lk = lane >> 4;
    const int m0 = blockIdx.x * BM;
    const int c0 = blockIdx.y * 64;
    const int mask = (1 << dlog) - 1;

    size_t a_goff[NCA]; int a_loff[NCA];
    int symL[NCA], symR[NCA];
#pragma unroll
    for (int j = 0; j < NCA; ++j) {
        int a = wid * NCA + j;
        int r_ = a * 16 + (lane >> 2);
        int kps = (lane & 3) ^ ((r_ >> 1) & 3);
        a_loff[j] = a * 512 + lane * 8;
        if constexpr (LEAF) {
            int rg = m0 + r_;
            int b_ = rg >> dlog, jj = rg & mask;
            int cbase = b_ * 127 + 2 * (node_base + jj) + 1;
            symL[j] = symbols[cbase];
            symR[j] = symbols[cbase + 1];
            a_goff[j] = kps * 8;
        } else {
            a_goff[j] = (size_t)(m0 + r_) * 1024 + kps * 8;
            symL[j] = symR[j] = 0;
        }
    }
    size_t b_goff[3]; int b_loff[3];
#pragma unroll
    for (int j = 0; j < 3; ++j) {
        int b = wid * 3 + j;
        int rr = b * 16 + (lane >> 2);
        int kps = (lane & 3) ^ ((rr >> 1) & 3);
        int grow = (rr >> 6) * 512 + c0 + (rr & 63);
        b_goff[j] = (size_t)grow * 1024 + kps * 8;
        b_loff[j] = b * 512 + lane * 8;
    }
    int a_roff[RF];
#pragma unroll
    for (int i = 0; i < RF; ++i) {
        int row = wr * (RF * 16) + i * 16 + lr;
        a_roff[i] = row * 32 + (lk ^ ((row >> 1) & 3)) * 8;
    }
    int b_roff[3][2];
#pragma unroll
    for (int s = 0; s < 3; ++s)
#pragma unroll
        for (int cf = 0; cf < 2; ++cf) {
            int row = s * 64 + wc * 32 + cf * 16 + lr;
            b_roff[s][cf] = row * 32 + (lk ^ ((row >> 1) & 3)) * 8;
        }

    f32x4 acc[4][2][RF];
#pragma unroll
    for (int s = 0; s < 4; ++s)
#pragma unroll
        for (int cf = 0; cf < 2; ++cf)
#pragma unroll
            for (int i = 0; i < RF; ++i) acc[s][cf][i] = (f32x4){0.f, 0.f, 0.f, 0.f};

    auto issue = [&](int stg) {
        const int buf = stg & 1;
        const int nk = stg * 32;
#pragma unroll
        for (int j = 0; j < NCA; ++j) {
            if constexpr (LEAF) {
                const u16* src = (nk < 512)
                    ? tab + (size_t)symL[j] * 512 + nk + a_goff[j]
                    : tab + (size_t)symR[j] * 512 + (nk - 512) + a_goff[j];
                gload16(src, &Als[buf][a_loff[j]]);
            } else {
                gload16(A + a_goff[j] + nk, &Als[buf][a_loff[j]]);
            }
        }
#pragma unroll
        for (int j = 0; j < 3; ++j) gload16(W + b_goff[j] + nk, &Bls[buf][b_loff[j]]);
    };
    auto compute = [&](int buf) {
        short8 a[RF];
#pragma unroll
        for (int i = 0; i < RF; ++i)
            a[i] = *reinterpret_cast<const short8*>(&Als[buf][a_roff[i]]);
#pragma unroll
        for (int s = 0; s < 3; ++s)
#pragma unroll
            for (int cf = 0; cf < 2; ++cf) {
                short8 b = *reinterpret_cast<const short8*>(&Bls[buf][b_roff[s][cf]]);
#pragma unroll
                for (int i = 0; i < RF; ++i)
                    acc[s][cf][i] = __builtin_amdgcn_mfma_f32_16x16x32_bf16(b, a[i], acc[s][cf][i], 0, 0, 0);
            }
    };

    issue(0);
    WAITV(0);
    __builtin_amdgcn_s_barrier();
    for (int t = 0; t < NS - 1; ++t) {
        issue(t + 1);
        compute(t & 1);
        WAITV(0);
        __builtin_amdgcn_s_barrier();
    }
    compute((NS - 1) & 1);

    {
        short8 oh[RF];
#pragma unroll
        for (int i = 0; i < RF; ++i) {
            int m = m0 + wr * (RF * 16) + i * 16 + lr;
            int b_ = m >> dlog, j_ = m & mask;
            oh[i] = *reinterpret_cast<const short8*>(
                oneh + (size_t)(b_ * 127 + node_base + j_) * 32 + lk * 8);
        }
#pragma unroll
        for (int s = 0; s < 3; ++s) {
            const int d = (s == 2) ? 3 : s;
#pragma unroll
            for (int cf = 0; cf < 2; ++cf) {
                short8 wb = *reinterpret_cast<const short8*>(
                    Wi + (size_t)(s * 512 + c0 + wc * 32 + cf * 16 + lr) * 32 + lk * 8);
#pragma unroll
                for (int i = 0; i < RF; ++i)
                    acc[d][cf][i] = __builtin_amdgcn_mfma_f32_16x16x32_bf16(wb, oh[i], acc[d][cf][i], 0, 0, 0);
            }
        }
    }

    float4 ebr4[2], ebz4[2], ebin4[2], ebhn4[2];
    int cb[2];
#pragma unroll
    for (int cf = 0; cf < 2; ++cf) {
        cb[cf] = c0 + wc * 32 + cf * 16 + lk * 4;
        float4 bi0 = *reinterpret_cast<const float4*>(ebi + cb[cf]);
        float4 bh0 = *reinterpret_cast<const float4*>(ebh + cb[cf]);
        float4 bi1 = *reinterpret_cast<const float4*>(ebi + 512 + cb[cf]);
        float4 bh1 = *reinterpret_cast<const float4*>(ebh + 512 + cb[cf]);
        ebr4[cf] = make_float4(bi0.x + bh0.x, bi0.y + bh0.y, bi0.z + bh0.z, bi0.w + bh0.w);
        ebz4[cf] = make_float4(bi1.x + bh1.x, bi1.y + bh1.y, bi1.z + bh1.z, bi1.w + bh1.w);
        ebin4[cf] = *reinterpret_cast<const float4*>(ebi + 1024 + cb[cf]);
        ebhn4[cf] = *reinterpret_cast<const float4*>(ebh + 1024 + cb[cf]);
    }
#pragma unroll
    for (int i = 0; i < RF; ++i) {
        int m = m0 + wr * (RF * 16) + i * 16 + lr;
        int symLm = 0, symRm = 0;
        if constexpr (LEAF) {
            int b_ = m >> dlog, jj = m & mask;
            int cbase_ = b_ * 127 + 2 * (node_base + jj) + 1;
            symLm = symbols[cbase_];
            symRm = symbols[cbase_ + 1];
        }
#pragma unroll
        for (int cf = 0; cf < 2; ++cf) {
            ushort4 hl4, hr4;
            if constexpr (LEAF) {
                hl4 = *reinterpret_cast<const ushort4*>(tab + (size_t)symLm * 512 + cb[cf]);
                hr4 = *reinterpret_cast<const ushort4*>(tab + (size_t)symRm * 512 + cb[cf]);
            } else {
                hl4 = *reinterpret_cast<const ushort4*>(A + (size_t)m * 1024 + cb[cf]);
                hr4 = *reinterpret_cast<const ushort4*>(A + (size_t)m * 1024 + 512 + cb[cf]);
            }
            const float eb_r[4] = {ebr4[cf].x, ebr4[cf].y, ebr4[cf].z, ebr4[cf].w};
            const float eb_z[4] = {ebz4[cf].x, ebz4[cf].y, ebz4[cf].z, ebz4[cf].w};
            const float eb_in[4] = {ebin4[cf].x, ebin4[cf].y, ebin4[cf].z, ebin4[cf].w};
            const float eb_hn[4] = {ebhn4[cf].x, ebhn4[cf].y, ebhn4[cf].z, ebhn4[cf].w};
            const u16 hlv[4] = {hl4.x, hl4.y, hl4.z, hl4.w};
            const u16 hrv[4] = {hr4.x, hr4.y, hr4.z, hr4.w};
            ushort4 outv;
            u16* ov = reinterpret_cast<u16*>(&outv);
#pragma unroll
            for (int r = 0; r < 4; ++r) {
                float rr_ = fsig(acc[0][cf][i][r] + eb_r[r]);
                float zz  = fsig(acc[1][cf][i][r] + eb_z[r]);
                float nn  = ftanh(acc[3][cf][i][r] + eb_in[r] + rr_ * (acc[2][cf][i][r] + eb_hn[r]));
                float hm = (bf2f(hlv[r]) + bf2f(hrv[r])) * 0.5f;
                ov[r] = f2bf((1.0f - zz) * nn + zz * hm);
            }
            *reinterpret_cast<ushort4*>(hout + (size_t)m * 512 + cb[cf]) = outv;
        }
    }
}

// ---------------- fused mid ----------------
__global__ __launch_bounds__(256) void midf(
    const u16* __restrict__ root, const float* __restrict__ h2mu_w,
    const float* __restrict__ h2mu_b, const float* __restrict__ h2lv_w,
    const float* __restrict__ h2lv_b, const float* __restrict__ eps,
    const float* __restrict__ z2h_w, const float* __restrict__ z2h_b,
    float* __restrict__ out_mu, float* __restrict__ out_lv,
    u16* __restrict__ hidden)
{
    int b = blockIdx.x, t = threadIdx.x;
    __shared__ float rs[512];
    __shared__ float zl[128];
    rs[t]       = bf2f(root[(size_t)b * 512 + t]);
    rs[t + 256] = bf2f(root[(size_t)b * 512 + t + 256]);
    __syncthreads();
    const float* w = (t < 128) ? (h2mu_w + (size_t)t * 512) : (h2lv_w + (size_t)(t - 128) * 512);
    float acc = 0.0f;
    for (int k = 0; k < 512; ++k) acc += rs[k] * w[k];
    acc += (t < 128) ? h2mu_b[t] : h2lv_b[t - 128];
    __shared__ float vals[256];
    vals[t] = acc;
    __syncthreads();
    if (t < 128) {
        float mu = vals[t], lv = vals[t + 128];
        zl[t] = mu + eps[b * 128 + t] * expf(0.5f * lv);
        out_mu[b * 128 + t] = mu;
        out_lv[b * 128 + t] = lv;
    }
    __syncthreads();
    for (int c = t; c < 512; c += 256) {
        float a2 = z2h_b[c];
        const float* wz = z2h_w + (size_t)c * 128;
        for (int k = 0; k < 128; ++k) a2 += zl[k] * wz[k];
        hidden[(size_t)b * 512 + c] = f2bf(a2);
    }
}

// ---------------- final pred (d=6): K-split across 4 waves + LDS reduce ----------------
__global__ __launch_bounds__(256) void pred_final(
    const u16* __restrict__ hidden, const u16* __restrict__ Wo,
    const float* __restrict__ h2o_b, float* __restrict__ preds_out)
{
    __shared__ float pbuf[4][32][17];
    const int tid = threadIdx.x;
    const int lane = tid & 63;
    const int w = tid >> 6;
    const int lr = lane & 15, lk = lane >> 4;
    const int m0 = blockIdx.x * 16;

    f32x4 acc0 = (f32x4){0.f, 0.f, 0.f, 0.f};
    f32x4 acc1 = (f32x4){0.f, 0.f, 0.f, 0.f};
    const u16* Arow = hidden + (size_t)(m0 + lr) * 512 + w * 128 + lk * 8;
    const u16* B0 = Wo + (size_t)lr * 512 + w * 128 + lk * 8;
    const u16* B1 = Wo + (size_t)(16 + lr) * 512 + w * 128 + lk * 8;
#pragma unroll
    for (int k0 = 0; k0 < 128; k0 += 32) {
        short8 a  = *reinterpret_cast<const short8*>(Arow + k0);
        short8 b0 = *reinterpret_cast<const short8*>(B0 + k0);
        short8 b1 = *reinterpret_cast<const short8*>(B1 + k0);
        acc0 = __builtin_amdgcn_mfma_f32_16x16x32_bf16(b0, a, acc0, 0, 0, 0);
        acc1 = __builtin_amdgcn_mfma_f32_16x16x32_bf16(b1, a, acc1, 0, 0, 0);
    }
#pragma unroll
    for (int r = 0; r < 4; ++r) {
        pbuf[w][lk * 4 + r][lr]      = acc0[r];
        pbuf[w][16 + lk * 4 + r][lr] = acc1[r];
    }
    __syncthreads();
#pragma unroll
    for (int it = 0; it < 2; ++it) {
        int o = tid + it * 256;
        int mloc = o >> 5, sym = o & 31;
        float p = pbuf[0][sym][mloc] + pbuf[1][sym][mloc]
                + pbuf[2][sym][mloc] + pbuf[3][sym][mloc] + h2o_b[sym];
        int m = m0 + mloc;
        int b_ = m >> 6, j_ = m & 63;
        preds_out[(size_t)(b_ * 127 + 63 + j_) * 32 + sym] = p;
    }
}

// ---------------- decoder: fused pred (wc-split halves) + softmax + GRU ----------------
template<int RF>
__global__ __launch_bounds__(256, 2) void dec_tile(
    const u16* __restrict__ Hin, const u16* __restrict__ Wh,
    const u16* __restrict__ Wi, const u16* __restrict__ Wo,
    const float* __restrict__ dbh, const float* __restrict__ dbi,
    const float* __restrict__ h2o_b, u16* __restrict__ Hout,
    float* __restrict__ preds_out, int dlog, int node_base)
{
    constexpr int BM = RF * 32;
    constexpr int NCA = BM / 64;
    constexpr int NS = 16;                 // K stages (512/32)
    __shared__ alignas(16) u16 Als[2][BM * 32];
    __shared__ alignas(16) u16 Bls[2][192 * 32];
    const int tid  = threadIdx.x;
    const int lane = tid & 63;
    const int wid  = tid >> 6;
    const int wr = wid >> 1, wc = wid & 1;
    const int lr = lane & 15, lk = lane >> 4;
    const int m0 = blockIdx.x * BM;
    const int c0 = blockIdx.y * 64;      // within 1024
    const int mask = (1 << dlog) - 1;

    size_t a_goff[NCA]; int a_loff[NCA];
#pragma unroll
    for (int j = 0; j < NCA; ++j) {
        int a = wid * NCA + j;
        int r_ = a * 16 + (lane >> 2);
        int kps = (lane & 3) ^ ((r_ >> 1) & 3);
        a_goff[j] = (size_t)(m0 + r_) * 512 + kps * 8;
        a_loff[j] = a * 512 + lane * 8;
    }
    size_t b_goff[3]; int b_loff[3];
#pragma unroll
    for (int j = 0; j < 3; ++j) {
        int b = wid * 3 + j;
        int rr = b * 16 + (lane >> 2);
        int kps = (lane & 3) ^ ((rr >> 1) & 3);
        int grow = (rr >> 6) * 1024 + c0 + (rr & 63);
        b_goff[j] = (size_t)grow * 512 + kps * 8;
        b_loff[j] = b * 512 + lane * 8;
    }
    int a_roff[RF];
#pragma unroll
    for (int i = 0; i < RF; ++i) {
        int row = wr * (RF * 16) + i * 16 + lr;
        a_roff[i] = row * 32 + (lk ^ ((row >> 1) & 3)) * 8;
    }
    int b_roff[3][2];
#pragma unroll
    for (int s = 0; s < 3; ++s)
#pragma unroll
        for (int cf = 0; cf < 2; ++cf) {
            int row = s * 64 + wc * 32 + cf * 16 + lr;
            b_roff[s][cf] = row * 32 + (lk ^ ((row >> 1) & 3)) * 8;
        }

    f32x4 acc[4][2][RF];
#pragma unroll
    for (int s = 0; s < 4; ++s)
#pragma unroll
        for (int cf = 0; cf < 2; ++cf)
#pragma unroll
            for (int i = 0; i < RF; ++i) acc[s][cf][i] = (f32x4){0.f, 0.f, 0.f, 0.f};
    // fused pred partial: this wave's symbol half = wc*16 + [0,16)
    f32x4 accp[RF];
#pragma unroll
    for (int i = 0; i < RF; ++i) accp[i] = (f32x4){0.f, 0.f, 0.f, 0.f};

    auto issue = [&](int stg) {
        const int buf = stg & 1;
        const int nk = stg * 32;
#pragma unroll
        for (int j = 0; j < NCA; ++j) gload16(Hin + a_goff[j] + nk, &Als[buf][a_loff[j]]);
#pragma unroll
        for (int j = 0; j < 3; ++j) gload16(Wh + b_goff[j] + nk, &Bls[buf][b_loff[j]]);
    };
    auto compute = [&](int buf, int t) {
        short8 a[RF];
#pragma unroll
        for (int i = 0; i < RF; ++i)
            a[i] = *reinterpret_cast<const short8*>(&Als[buf][a_roff[i]]);
#pragma unroll
        for (int s = 0; s < 3; ++s)
#pragma unroll
            for (int cf = 0; cf < 2; ++cf) {
                short8 b = *reinterpret_cast<const short8*>(&Bls[buf][b_roff[s][cf]]);
#pragma unroll
                for (int i = 0; i < RF; ++i)
                    acc[s][cf][i] = __builtin_amdgcn_mfma_f32_16x16x32_bf16(b, a[i], acc[s][cf][i], 0, 0, 0);
            }
        // balanced fused pred: wc0 -> symbols 0..15, wc1 -> symbols 16..31 (4 MFMA/step each)
        {
            short8 wo = *reinterpret_cast<const short8*>(
                Wo + (size_t)(wc * 16 + lr) * 512 + t * 32 + lk * 8);
#pragma unroll
            for (int i = 0; i < RF; ++i)
                accp[i] = __builtin_amdgcn_mfma_f32_16x16x32_bf16(wo, a[i], accp[i], 0, 0, 0);
        }
    };

    issue(0);
    WAITV(0);
    __builtin_amdgcn_s_barrier();
    for (int t = 0; t < NS - 1; ++t) {
        issue(t + 1);
        compute(t & 1, t);
        WAITV(0);
        __builtin_amdgcn_s_barrier();
    }
    compute((NS - 1) & 1, NS - 1);

    // ---- exchange wc1's pred half via LDS (Bls[0] free: last compute read buf 1) ----
    float* pexch = reinterpret_cast<float*>(&Bls[0][0]);   // [wr][i][r][lk][lr] = 8KB @RF4
    if (wc == 1) {
#pragma unroll
        for (int i = 0; i < RF; ++i)
#pragma unroll
            for (int r = 0; r < 4; ++r)
                pexch[(((wr * RF + i) * 4 + r) * 4 + lk) * 16 + lr] = accp[i][r];
    }
    __builtin_amdgcn_s_barrier();

    // ---- softmax + write preds (y==0) + stage a into LDS -- wc==0 waves ----
    u16* aLds = &Als[0][0];     // BM x 32 bf16 (Als[0] dead since loop's last barrier)
    if (wc == 0) {
        float4 bb0 = *reinterpret_cast<const float4*>(h2o_b + lk * 4);
        float4 bb1 = *reinterpret_cast<const float4*>(h2o_b + 16 + lk * 4);
#pragma unroll
        for (int i = 0; i < RF; ++i) {
            float p0[4], p1[4];
            p0[0] = accp[i][0] + bb0.x; p0[1] = accp[i][1] + bb0.y;
            p0[2] = accp[i][2] + bb0.z; p0[3] = accp[i][3] + bb0.w;
#pragma unroll
            for (int r = 0; r < 4; ++r)
                p1[r] = pexch[(((wr * RF + i) * 4 + r) * 4 + lk) * 16 + lr];
            p1[0] += bb1.x; p1[1] += bb1.y; p1[2] += bb1.z; p1[3] += bb1.w;
            float mx = fmaxf(fmaxf(fmaxf(p0[0], p0[1]), fmaxf(p0[2], p0[3])),
                             fmaxf(fmaxf(p1[0], p1[1]), fmaxf(p1[2], p1[3])));
            mx = fmaxf(mx, __shfl_xor(mx, 16));
            mx = fmaxf(mx, __shfl_xor(mx, 32));
            float e0[4], e1[4], s = 0.0f;
#pragma unroll
            for (int r = 0; r < 4; ++r) {
                e0[r] = __expf(p0[r] - mx); e1[r] = __expf(p1[r] - mx);
                s += e0[r] + e1[r];
            }
            s += __shfl_xor(s, 16);
            s += __shfl_xor(s, 32);
            int mloc = wr * (RF * 16) + i * 16 + lr;
            int m = m0 + mloc;
            if (blockIdx.y == 0) {
                int b_ = m >> dlog, j_ = m & mask;
                size_t o = (size_t)(b_ * 127 + node_base + j_) * 32;
                *reinterpret_cast<float4*>(preds_out + o + lk * 4)      = make_float4(p0[0], p0[1], p0[2], p0[3]);
                *reinterpret_cast<float4*>(preds_out + o + 16 + lk * 4) = make_float4(p1[0], p1[1], p1[2], p1[3]);
            }
            float inv = __builtin_amdgcn_rcpf(s);
            ushort4 a0, a1;
            u16* av0 = reinterpret_cast<u16*>(&a0);
            u16* av1 = reinterpret_cast<u16*>(&a1);
#pragma unroll
            for (int r = 0; r < 4; ++r) { av0[r] = f2bf(e0[r] * inv); av1[r] = f2bf(e1[r] * inv); }
            *reinterpret_cast<ushort4*>(aLds + mloc * 32 + lk * 4)      = a0;
            *reinterpret_cast<ushort4*>(aLds + mloc * 32 + 16 + lk * 4) = a1;
        }
    }
    __builtin_amdgcn_s_barrier();

    // rank-32 input-gate contribution (a from LDS)
#pragma unroll
    for (int i = 0; i < RF; ++i) {
        int mloc = wr * (RF * 16) + i * 16 + lr;
        short8 aw = *reinterpret_cast<const short8*>(aLds + mloc * 32 + lk * 8);
#pragma unroll
        for (int s = 0; s < 3; ++s) {
            const int d = (s == 2) ? 3 : s;
#pragma unroll
            for (int cf = 0; cf < 2; ++cf) {
                short8 b = *reinterpret_cast<const short8*>(
                    Wi + (size_t)(s * 1024 + c0 + wc * 32 + cf * 16 + lr) * 32 + lk * 8);
                acc[d][cf][i] = __builtin_amdgcn_mfma_f32_16x16x32_bf16(b, aw, acc[d][cf][i], 0, 0, 0);
            }
        }
    }

    // ---- epilogue ----
    float4 br4[2], bz4[2], bin4[2], bhn4[2];
    int cb[2];
#pragma unroll
    for (int cf = 0; cf < 2; ++cf) {
        cb[cf] = c0 + wc * 32 + cf * 16 + lk * 4;
        float4 h0 = *reinterpret_cast<const float4*>(dbh + cb[cf]);
        float4 i0 = *reinterpret_cast<const float4*>(dbi + cb[cf]);
        float4 h1 = *reinterpret_cast<const float4*>(dbh + 1024 + cb[cf]);
        float4 i1 = *reinterpret_cast<const float4*>(dbi + 1024 + cb[cf]);
        br4[cf] = make_float4(h0.x + i0.x, h0.y + i0.y, h0.z + i0.z, h0.w + i0.w);
        bz4[cf] = make_float4(h1.x + i1.x, h1.y + i1.y, h1.z + i1.z, h1.w + i1.w);
        bin4[cf] = *reinterpret_cast<const float4*>(dbi + 2048 + cb[cf]);
        bhn4[cf] = *reinterpret_cast<const float4*>(dbh + 2048 + cb[cf]);
    }
#pragma unroll
    for (int i = 0; i < RF; ++i) {
        int m = m0 + wr * (RF * 16) + i * 16 + lr;
#pragma unroll
        for (int cf = 0; cf < 2; ++cf) {
            ushort4 hid4 = *reinterpret_cast<const ushort4*>(Hin + (size_t)m * 512 + (cb[cf] & 511));
            const float b_r[4] = {br4[cf].x, br4[cf].y, br4[cf].z, br4[cf].w};
            const float b_z[4] = {bz4[cf].x, bz4[cf].y, bz4[cf].z, bz4[cf].w};
            const float b_in[4] = {bin4[cf].x, bin4[cf].y, bin4[cf].z, bin4[cf].w};
            const float b_hn[4] = {bhn4[cf].x, bhn4[cf].y, bhn4[cf].z, bhn4[cf].w};
            const u16 hv[4] = {hid4.x, hid4.y, hid4.z, hid4.w};
            ushort4 outv;
            u16* ov = reinterpret_cast<u16*>(&outv);
#pragma unroll
            for (int r = 0; r < 4; ++r) {
                float rr_ = fsig(acc[0][cf][i][r] + b_r[r]);
                float zz  = fsig(acc[1][cf][i][r] + b_z[r]);
                float nn  = ftanh(acc[3][cf][i][r] + b_in[r] + rr_ * (acc[2][cf][i][r] + b_hn[r]));
                ov[r] = f2bf((1.0f - zz) * nn + zz * bf2f(hv[r]));
            }
            *reinterpret_cast<ushort4*>(Hout + (size_t)m * 1024 + cb[cf]) = outv;
        }
    }
}

extern "C" void kernel_launch(void* const* d_in, const int* in_sizes, int n_in,
                              void* d_out, int out_size, void* d_ws, size_t ws_size,
                              hipStream_t stream) {
    const int*   symbols = (const int*)  d_in[0];
    const float* eps     = (const float*)d_in[1];
    const float* ewi     = (const float*)d_in[2];
    const float* ebi     = (const float*)d_in[3];
    const float* ewh     = (const float*)d_in[4];
    const float* ebh     = (const float*)d_in[5];
    const float* h2mu_w  = (const float*)d_in[6];
    const float* h2mu_b  = (const float*)d_in[7];
    const float* h2lv_w  = (const float*)d_in[8];
    const float* h2lv_b  = (const float*)d_in[9];
    const float* z2h_w   = (const float*)d_in[10];
    const float* z2h_b   = (const float*)d_in[11];
    const float* h2o_w   = (const float*)d_in[12];
    const float* h2o_b   = (const float*)d_in[13];
    const float* dwi     = (const float*)d_in[14];
    const float* dbi     = (const float*)d_in[15];
    const float* dwh     = (const float*)d_in[16];
    const float* dbh     = (const float*)d_in[17];

    float* out    = (float*)d_out;
    float* out_mu = out;
    float* out_lv = out + 256 * 128;
    float* out_pr = out + 2 * 256 * 128;

    // ---- workspace layout (~34.6 MB) ----
    u16* bufL  = (u16*)d_ws;                            // 16384*512
    u16* bufS  = bufL  + (size_t)16384 * 512;           //  8192*512
    u16* ewh_b = bufS  + (size_t)8192 * 512;            // 1536*1024
    u16* dwh_b = ewh_b + (size_t)1536 * 1024;           // 3072*512
    u16* dwi_b = dwh_b + (size_t)3072 * 512;            // 3072*32
    u16* ewi_b = dwi_b + (size_t)3072 * 32;             // 1536*32
    u16* wo_b  = ewi_b + (size_t)1536 * 32;             // 32*512
    u16* ltab  = wo_b  + (size_t)32 * 512;              // 32*512
    u16* oneh  = ltab  + (size_t)32 * 512;              // 32512*32

    // ---- single merged prep launch (vec4) ----
    prep<<<(1091584 + 255) / 256, 256, 0, stream>>>(
        ewh, dwh, dwi, ewi, h2o_w, symbols, ebi, ebh,
        ewh_b, dwh_b, dwi_b, ewi_b, wo_b, oneh, ltab);

    // ---- encoder ---- d=5 fused with leaf (reads tab directly), writes bufS
    enc_tile<4, true><<<dim3(64, 8), 256, 0, stream>>>(
        nullptr, ewh_b, oneh, ewi_b, ltab, symbols, ebi, ebh, bufS, 5, 31);
    const u16* src = bufS;
    u16*       dst = bufL;
    for (int d = 4; d >= 0; --d) {
        int M = 256 << d;
        if (M >= 4096)
            enc_tile<4, false><<<dim3(M / 128, 8), 256, 0, stream>>>(
                src, ewh_b, oneh, ewi_b, ltab, symbols, ebi, ebh, dst, d, (1 << d) - 1);
        else
            enc_tile<2, false><<<dim3(M / 64, 8), 256, 0, stream>>>(
                src, ewh_b, oneh, ewi_b, ltab, symbols, ebi, ebh, dst, d, (1 << d) - 1);
        const u16* t = src; src = dst; dst = (u16*)t;
    }
    // root in bufL
    midf<<<256, 256, 0, stream>>>(src, h2mu_w, h2mu_b, h2lv_w, h2lv_b, eps,
                                  z2h_w, z2h_b, out_mu, out_lv, bufL);

    // ---- decoder (pred fused into dec_tile, wc-split) ----
    const u16* hsrc = bufL;
    u16*       hdst = bufS;
    for (int d = 0; d < 6; ++d) {
        int M = 256 << d;
        if (M >= 4096)
            dec_tile<4><<<dim3(M / 128, 16), 256, 0, stream>>>(
                hsrc, dwh_b, dwi_b, wo_b, dbh, dbi, h2o_b, hdst, out_pr, d, (1 << d) - 1);
        else
            dec_tile<2><<<dim3(M / 64, 16), 256, 0, stream>>>(
                hsrc, dwh_b, dwi_b, wo_b, dbh, dbi, h2o_b, hdst, out_pr, d, (1 << d) - 1);
        const u16* t = hsrc; hsrc = hdst; hdst = (u16*)t;
    }
    pred_final<<<16384 / 16, 256, 0, stream>>>(hsrc, wo_b, h2o_b, out_pr);
}